// Round 4
// baseline (601.338 us; speedup 1.0000x reference)
//
#include <hip/hip_runtime.h>
#include <cstdint>
#include <cstddef>

typedef unsigned short u16;
typedef __attribute__((ext_vector_type(8))) short short8;
typedef __attribute__((ext_vector_type(4))) float floatx4;
typedef __attribute__((ext_vector_type(16))) float floatx16;

__device__ __forceinline__ u16 f2bf(float f) {
  unsigned u = __float_as_uint(f);
  u += 0x7fffu + ((u >> 16) & 1u);
  return (u16)(u >> 16);
}
__device__ __forceinline__ float bf2f(u16 s) {
  return __uint_as_float(((unsigned)s) << 16);
}

// ---------------- LayerNorm (f32 in) -> bf16 x ----------------
__global__ __launch_bounds__(256) void ln_kernel(const float* __restrict__ x,
                                                 const float* __restrict__ g,
                                                 const float* __restrict__ bta,
                                                 u16* __restrict__ out) {
  const int row = blockIdx.x;
  const int tid = threadIdx.x;
  const float4 v = ((const float4*)(x + (size_t)row * 1024))[tid];
  float s = v.x + v.y + v.z + v.w;
#pragma unroll
  for (int o = 32; o > 0; o >>= 1) s += __shfl_down(s, o);
  __shared__ float red[4], red2[4];
  const int wv = tid >> 6, ln = tid & 63;
  if (ln == 0) red[wv] = s;
  __syncthreads();
  const float mean = (red[0] + red[1] + red[2] + red[3]) * (1.0f / 1024.0f);
  const float dx = v.x - mean, dy = v.y - mean, dz = v.z - mean, dw = v.w - mean;
  float s2 = dx * dx + dy * dy + dz * dz + dw * dw;
#pragma unroll
  for (int o = 32; o > 0; o >>= 1) s2 += __shfl_down(s2, o);
  if (ln == 0) red2[wv] = s2;
  __syncthreads();
  const float var = (red2[0] + red2[1] + red2[2] + red2[3]) * (1.0f / 1024.0f);
  const float rstd = rsqrtf(var + 1e-6f);
  const float4 gg = ((const float4*)g)[tid];
  const float4 bb = ((const float4*)bta)[tid];
  ushort4 o4;
  o4.x = f2bf(dx * rstd * gg.x + bb.x);
  o4.y = f2bf(dy * rstd * gg.y + bb.y);
  o4.z = f2bf(dz * rstd * gg.z + bb.z);
  o4.w = f2bf(dw * rstd * gg.w + bb.w);
  ((ushort4*)(out + (size_t)row * 1024))[tid] = o4;
}

// ---------------- W (KxN f32) -> WT (NxK bf16) ----------------
__global__ __launch_bounds__(256) void transpose_bf16(const float* __restrict__ W,
                                                      u16* __restrict__ WT,
                                                      int K, int N) {
  __shared__ float t[32][33];
  const int kb = blockIdx.x * 32, nb = blockIdx.y * 32;
  const int tx = threadIdx.x & 31, ty = threadIdx.x >> 5;
#pragma unroll
  for (int i = ty; i < 32; i += 8) t[i][tx] = W[(size_t)(kb + i) * N + nb + tx];
  __syncthreads();
#pragma unroll
  for (int i = ty; i < 32; i += 8) WT[(size_t)(nb + i) * K + kb + tx] = f2bf(t[tx][i]);
}

// ================= 256x256 pipelined bf16 MFMA GEMM (32x32x16) =================
// C = A(MxK) * BT(NxK)^T + bias.  512 threads = 8 waves (2M x 4N), BK=64,
// LDS = 2 dbuf x (A 256x64 + B 256x64) bf16 = 128 KiB -> 1 block/CU.
// 32x32x16 MFMA (lower matrix floor than 16x16x32), B0 retained in regs
// (24 LDS reads/wave/tile), reads issued a pack early (counted lgkmcnt with
// sched_barrier-pinned issue order) so the LDS pipe runs under the matrix-pipe
// drain. 2 barriers/tile; counted vmcnt(4) at the boundary (never 0 mid-loop).

__device__ __forceinline__ void stageG(const u16* __restrict__ gp, u16* lp, int K) {
  // rows srow and srow+64 of a 128-row half-tile; lane adds 16B at HW level
  __builtin_amdgcn_global_load_lds((const __attribute__((address_space(1))) void*)gp,
                                   (__attribute__((address_space(3))) void*)lp, 16, 0, 0);
  __builtin_amdgcn_global_load_lds((const __attribute__((address_space(1))) void*)(gp + ((size_t)K << 6)),
                                   (__attribute__((address_space(3))) void*)(lp + 4096), 16, 0, 0);
}

// A fragments: 2 row-tiles (32 rows) x 4 k-steps (K=16 each)
__device__ __forceinline__ void rdA(short8 (&af)[2][4], const u16* sbuf, const int (&ab)[4],
                                    int halfoff) {
#pragma unroll
  for (int mi = 0; mi < 2; ++mi)
#pragma unroll
    for (int ks = 0; ks < 4; ++ks)
      af[mi][ks] = *(const short8*)(sbuf + halfoff + mi * 2048 + ab[ks]);
}
// B fragments: 1 col-tile (32 cols) x 4 k-steps
__device__ __forceinline__ void rdB(short8 (&bf)[4], const u16* sbuf, const int (&bb)[4],
                                    int halfoff) {
#pragma unroll
  for (int ks = 0; ks < 4; ++ks)
    bf[ks] = *(const short8*)(sbuf + halfoff + bb[ks]);
}

template <int Q>
__device__ __forceinline__ void mfmaQ(floatx16 (&acc)[4][2], const short8 (&af)[2][4],
                                      const short8 (&bf)[4]) {
#pragma unroll
  for (int ks = 0; ks < 4; ++ks)
#pragma unroll
    for (int mi = 0; mi < 2; ++mi)
      acc[Q][mi] = __builtin_amdgcn_mfma_f32_32x32x16_bf16(af[mi][ks], bf[ks], acc[Q][mi], 0, 0, 0);
}

// One K-tile. Quadrants (0,0)->(0,1)->(1,1)->(1,0) = acc[0..3].
// Stages: pre-P1: A1(t+1); P1: B0(t+1); post-alpha: A0(t+2); P3: B1(t+2).
// Boundary: vmcnt(4) keeps {A0(t+2), B1(t+2)} in flight.
template <int B_>
__device__ __forceinline__ void gtile(int t, int NT, int K,
                                      u16 (&sA)[2][16384], u16 (&sB)[2][16384],
                                      const u16* gA_lo, const u16* gA_hi,
                                      const u16* gB_lo, const u16* gB_hi,
                                      u16* ldsA_cur, u16* ldsA_alt,
                                      u16* ldsB_cur, u16* ldsB_alt,
                                      const int (&ab)[4], const int (&bb)[4],
                                      floatx16 (&acc)[4][2]) {
  short8 af[2][4], bf0[4], bf1[4];
  // post-boundary: read A0, B0 (12 ds_reads), pin order, then stage + read B1.
  rdA(af, sA[B_], ab, 0);
  rdB(bf0, sB[B_], bb, 0);
  // pin: the 12 A0/B0 reads are strictly older than the 4 B1 reads below,
  // making the counted lgkmcnt(4) at P1 correct by construction.
  __builtin_amdgcn_sched_barrier(0);
  if (t + 1 < NT) stageG(gA_hi + ((t + 1) << 6), ldsA_alt + 8192, K);
  rdB(bf1, sB[B_], bb, 8192);
  // P1: A0 x B0 (A0/B0 complete; B1's 4 reads may remain outstanding)
  asm volatile("s_waitcnt lgkmcnt(4)" ::: "memory");
  __builtin_amdgcn_sched_barrier(0);
  __builtin_amdgcn_s_setprio(1);
  mfmaQ<0>(acc, af, bf0);
  __builtin_amdgcn_s_setprio(0);
  if (t + 1 < NT) stageG(gB_lo + ((t + 1) << 6), ldsB_alt, K);
  // P2: A0 x B1
  asm volatile("s_waitcnt lgkmcnt(0)" ::: "memory");
  __builtin_amdgcn_sched_barrier(0);
  __builtin_amdgcn_s_setprio(1);
  mfmaQ<1>(acc, af, bf1);
  __builtin_amdgcn_s_setprio(0);
  // prefetch A1 into af (WAR; reads half1, disjoint from post-alpha A0 stage)
  rdA(af, sA[B_], ab, 8192);
  // alpha: all waves have waited their A0/B0/B1 reads -> current-buffer staging safe
  __builtin_amdgcn_s_barrier();
  if (t + 2 < NT) stageG(gA_lo + ((t + 2) << 6), ldsA_cur, K);
  // P3: A1 x B1
  asm volatile("s_waitcnt lgkmcnt(0)" ::: "memory");
  __builtin_amdgcn_sched_barrier(0);
  __builtin_amdgcn_s_setprio(1);
  mfmaQ<2>(acc, af, bf1);
  __builtin_amdgcn_s_setprio(0);
  if (t + 2 < NT) stageG(gB_hi + ((t + 2) << 6), ldsB_cur + 8192, K);
  // P4: A1 x B0 (both operand sets resident in registers -> no wait)
  __builtin_amdgcn_s_setprio(1);
  mfmaQ<3>(acc, af, bf0);
  __builtin_amdgcn_s_setprio(0);
  if (t + 2 < NT) {
    asm volatile("s_waitcnt vmcnt(4)" ::: "memory");
  } else {
    asm volatile("s_waitcnt vmcnt(0)" ::: "memory");
  }
  __builtin_amdgcn_s_barrier();
}

template <int EPI>
__global__ __launch_bounds__(512, 2) void gemm_bf16(const u16* __restrict__ A,
                                                    const u16* __restrict__ BT,
                                                    const float* __restrict__ bias,
                                                    const float* __restrict__ extra,
                                                    u16* __restrict__ outB,
                                                    float* __restrict__ outF,
                                                    int M, int N, int K) {
  __shared__ u16 sA[2][16384];
  __shared__ u16 sB[2][16384];
  const int tid = threadIdx.x;
  const int wave = tid >> 6, lane = tid & 63;
  const int m0 = blockIdx.x * 256, n0 = blockIdx.y * 256;
  const int wr = wave >> 2, wc = wave & 3;  // 2x4 wave grid within a quadrant
  const int l31 = lane & 31, l5 = lane >> 5, l7 = lane & 7;
  const int NT = K >> 6;  // requires K % 128 == 0, K >= 192

  // LDS fragment base offsets (u16 units): row*64 + xor-slot; mi adds 2048, half adds 8192
  int ab[4], bb[4];
#pragma unroll
  for (int ks = 0; ks < 4; ++ks) {
    const int xr = ((((ks << 1) + l5) ^ l7) << 3);
    ab[ks] = (wr * 64 + l31) * 64 + xr;
    bb[ks] = (wc * 32 + l31) * 64 + xr;
  }
  // staging source pointers (per lane); column advance via t*64 at call sites
  const int srow = wave * 8 + (lane >> 3);
  const int scol = ((lane & 7) ^ (srow & 7)) << 3;
  const u16* gA_lo = A + (size_t)(m0 + srow) * K + scol;
  const u16* gA_hi = A + (size_t)(m0 + 128 + srow) * K + scol;
  const u16* gB_lo = BT + (size_t)(n0 + srow) * K + scol;
  const u16* gB_hi = BT + (size_t)(n0 + 128 + srow) * K + scol;

  floatx16 acc[4][2];
#pragma unroll
  for (int q = 0; q < 4; ++q)
#pragma unroll
    for (int mi = 0; mi < 2; ++mi)
#pragma unroll
      for (int r = 0; r < 16; ++r) acc[q][mi][r] = 0.f;

  // prologue: tile0 fully (8 loads) + A0(1), B1(1) (4 loads) -> vmcnt(4) = tile0 landed
  stageG(gA_lo, &sA[0][0] + wave * 512, K);
  stageG(gA_hi, &sA[0][8192] + wave * 512, K);
  stageG(gB_lo, &sB[0][0] + wave * 512, K);
  stageG(gB_hi, &sB[0][8192] + wave * 512, K);
  stageG(gA_lo + 64, &sA[1][0] + wave * 512, K);
  stageG(gB_hi + 64, &sB[1][8192] + wave * 512, K);
  asm volatile("s_waitcnt vmcnt(4)" ::: "memory");
  __builtin_amdgcn_s_barrier();

  for (int t = 0; t < NT; t += 2) {
    gtile<0>(t, NT, K, sA, sB, gA_lo, gA_hi, gB_lo, gB_hi,
             &sA[0][0] + wave * 512, &sA[1][0] + wave * 512,
             &sB[0][0] + wave * 512, &sB[1][0] + wave * 512, ab, bb, acc);
    gtile<1>(t + 1, NT, K, sA, sB, gA_lo, gA_hi, gB_lo, gB_hi,
             &sA[1][0] + wave * 512, &sA[0][0] + wave * 512,
             &sB[1][0] + wave * 512, &sB[0][0] + wave * 512, ab, bb, acc);
  }

  // epilogue: 32x32 C/D layout: col = lane&31, row = (reg&3) + 8*(reg>>2) + 4*(lane>>5)
#pragma unroll
  for (int q = 0; q < 4; ++q) {
    const int QM = q >> 1, QN = QM ^ (q & 1);
    const int n = n0 + QN * 128 + wc * 32 + l31;
    const float bs = bias[n];
#pragma unroll
    for (int mi = 0; mi < 2; ++mi) {
      const int mb = m0 + QM * 128 + wr * 64 + mi * 32 + 4 * l5;
#pragma unroll
      for (int reg = 0; reg < 16; ++reg) {
        const int m = mb + (reg & 3) + 8 * (reg >> 2);
        const float v = acc[q][mi][reg] + bs;
        if (EPI == 0)
          outB[(size_t)m * N + n] = f2bf(v);
        else
          outF[(size_t)m * N + n] = v + extra[(size_t)m * N + n];
      }
    }
  }
}

// ---------------- attn1 stage A: scores S[bh][a][n] ----------------
__global__ __launch_bounds__(256) void attn1_scores(const u16* __restrict__ qkv,
                                                    const float* __restrict__ q_anchor,
                                                    float* __restrict__ S) {
  __shared__ float qa[8][128];
  const int tid = threadIdx.x;
  const int chunk = blockIdx.x & 7, bh = blockIdx.x >> 3;
  const int b = bh >> 3, h = bh & 7;
  for (int i = tid; i < 1024; i += 256) qa[i >> 7][i & 127] = q_anchor[h * 1024 + i];
  __syncthreads();
  const float scale = 0.0883883476483184f;
  const int n = chunk * 256 + tid;
  const u16* kp = qkv + (size_t)(b * 2048 + n) * 3072 + 1024 + h * 128;
  float dots[8] = {0, 0, 0, 0, 0, 0, 0, 0};
#pragma unroll 8
  for (int dd = 0; dd < 128; dd += 4) {
    const ushort4 k4 = *(const ushort4*)(kp + dd);
    const float k0 = bf2f(k4.x), k1 = bf2f(k4.y), k2 = bf2f(k4.z), k3 = bf2f(k4.w);
#pragma unroll
    for (int a = 0; a < 8; ++a) {
      const float4 q4 = *(const float4*)&qa[a][dd];
      dots[a] += q4.x * k0 + q4.y * k1 + q4.z * k2 + q4.w * k3;
    }
  }
#pragma unroll
  for (int a = 0; a < 8; ++a) S[((size_t)(bh * 8 + a)) * 2048 + n] = dots[a] * scale;
}

// ---------------- attn1 stage B: row softmax over 2048, in place ----------------
__global__ __launch_bounds__(256) void attn1_softmax(float* __restrict__ S) {
  const int row = blockIdx.x;
  const int tid = threadIdx.x;
  float* Sp = S + (size_t)row * 2048;
  float4 v0 = ((const float4*)Sp)[tid * 2];
  float4 v1 = ((const float4*)Sp)[tid * 2 + 1];
  float mx = fmaxf(fmaxf(fmaxf(v0.x, v0.y), fmaxf(v0.z, v0.w)),
                   fmaxf(fmaxf(v1.x, v1.y), fmaxf(v1.z, v1.w)));
#pragma unroll
  for (int o = 32; o > 0; o >>= 1) mx = fmaxf(mx, __shfl_xor(mx, o));
  __shared__ float red[4];
  const int wv = tid >> 6, ln = tid & 63;
  if (ln == 0) red[wv] = mx;
  __syncthreads();
  mx = fmaxf(fmaxf(red[0], red[1]), fmaxf(red[2], red[3]));
  v0.x = __expf(v0.x - mx); v0.y = __expf(v0.y - mx);
  v0.z = __expf(v0.z - mx); v0.w = __expf(v0.w - mx);
  v1.x = __expf(v1.x - mx); v1.y = __expf(v1.y - mx);
  v1.z = __expf(v1.z - mx); v1.w = __expf(v1.w - mx);
  float sum = v0.x + v0.y + v0.z + v0.w + v1.x + v1.y + v1.z + v1.w;
#pragma unroll
  for (int o = 32; o > 0; o >>= 1) sum += __shfl_xor(sum, o);
  __shared__ float red2[4];
  if (ln == 0) red2[wv] = sum;
  __syncthreads();
  const float inv = 1.f / (red2[0] + red2[1] + red2[2] + red2[3]);
  v0.x *= inv; v0.y *= inv; v0.z *= inv; v0.w *= inv;
  v1.x *= inv; v1.y *= inv; v1.z *= inv; v1.w *= inv;
  ((float4*)Sp)[tid * 2] = v0;
  ((float4*)Sp)[tid * 2 + 1] = v1;
}

// ---------------- attn1 stage C: partial PV -> pvpart[16 splits][64][1024] ----------------
__global__ __launch_bounds__(256) void attn1_pv(const u16* __restrict__ qkv,
                                                const float* __restrict__ S,
                                                float* __restrict__ pvpart) {
  __shared__ float P[8][256];
  const int tid = threadIdx.x;
  const int chunk = blockIdx.x & 7, bh = blockIdx.x >> 3;
  const int b = bh >> 3, h = bh & 7;
  for (int i = tid; i < 2048; i += 256) {
    const int a = i >> 8, n = i & 255;
    P[a][n] = S[((size_t)(bh * 8 + a)) * 2048 + chunk * 256 + n];
  }
  __syncthreads();
  const int d = tid & 127, half = tid >> 7;
  const int nbase = chunk * 256 + half * 128;
  const u16* vp = qkv + (size_t)(b * 2048 + nbase) * 3072 + 2048 + h * 128 + d;
  float acc[8] = {0.f};
  for (int n = 0; n < 128; n += 4) {
    const float v0 = bf2f(vp[(size_t)n * 3072]);
    const float v1 = bf2f(vp[(size_t)(n + 1) * 3072]);
    const float v2 = bf2f(vp[(size_t)(n + 2) * 3072]);
    const float v3 = bf2f(vp[(size_t)(n + 3) * 3072]);
#pragma unroll
    for (int a = 0; a < 8; ++a) {
      const float4 s4 = *(const float4*)&P[a][half * 128 + n];
      acc[a] += s4.x * v0 + s4.y * v1 + s4.z * v2 + s4.w * v3;
    }
  }
  const int split = chunk * 2 + half;
#pragma unroll
  for (int a = 0; a < 8; ++a)
    pvpart[((size_t)split * 64 + bh) * 1024 + a * 128 + d] = acc[a];
}

// ---------------- MLP MFMA GEMM: part[split][64][N] = A[64][Kc] @ W[Kc][N] ----------------
__global__ __launch_bounds__(256) void mlp_mfma(const float* __restrict__ A,
                                                const float* __restrict__ W,
                                                float* __restrict__ part,
                                                int K, int N, int KC) {
  __shared__ float sW[64][33];
  const int tid = threadIdx.x;
  const int lane = tid & 63, wave = tid >> 6;
  const int wm = wave * 16;
  const int n0 = blockIdx.x * 64;
  const int kbeg = blockIdx.y * KC;
  const int l15 = lane & 15, kq8 = (lane >> 4) * 8;
  const int arow = wm + l15;

  floatx4 acc[4];
  const floatx4 zero = {0.f, 0.f, 0.f, 0.f};
#pragma unroll
  for (int j = 0; j < 4; ++j) acc[j] = zero;

  for (int kc = 0; kc < KC; kc += 32) {
    const int kbase = kbeg + kc;
    __syncthreads();
#pragma unroll
    for (int p = 0; p < 8; ++p) {
      const int k = p * 4 + wave;
      sW[lane][k] = W[(size_t)(kbase + k) * N + n0 + lane];
    }
    const float* ap = A + (size_t)arow * K + kbase + kq8;
    const float4 a0 = *(const float4*)ap;
    const float4 a1 = *(const float4*)(ap + 4);
    short8 af;
    af[0] = (short)f2bf(a0.x); af[1] = (short)f2bf(a0.y);
    af[2] = (short)f2bf(a0.z); af[3] = (short)f2bf(a0.w);
    af[4] = (short)f2bf(a1.x); af[5] = (short)f2bf(a1.y);
    af[6] = (short)f2bf(a1.z); af[7] = (short)f2bf(a1.w);
    __syncthreads();
#pragma unroll
    for (int j = 0; j < 4; ++j) {
      const float* wp = &sW[j * 16 + l15][kq8];
      short8 bf;
      bf[0] = (short)f2bf(wp[0]); bf[1] = (short)f2bf(wp[1]);
      bf[2] = (short)f2bf(wp[2]); bf[3] = (short)f2bf(wp[3]);
      bf[4] = (short)f2bf(wp[4]); bf[5] = (short)f2bf(wp[5]);
      bf[6] = (short)f2bf(wp[6]); bf[7] = (short)f2bf(wp[7]);
      acc[j] = __builtin_amdgcn_mfma_f32_16x16x32_bf16(af, bf, acc[j], 0, 0, 0);
    }
  }
  const int q = lane >> 4;
#pragma unroll
  for (int j = 0; j < 4; ++j)
#pragma unroll
    for (int r = 0; r < 4; ++r) {
      const int m = wm + q * 4 + r;
      const int n = n0 + j * 16 + l15;
      part[((size_t)blockIdx.y * 64 + m) * N + n] = acc[j][r];
    }
}

// ---------------- reduce: out = [relu](sum_s part + bias), optional an-permute ----------------
__global__ __launch_bounds__(256) void mlp_reduce(const float* __restrict__ part,
                                                  const float* __restrict__ bias,
                                                  float* __restrict__ out,
                                                  int N, int nsplit, int relu, int perm) {
  const int idx = blockIdx.x * 256 + threadIdx.x;
  const int e = idx * 4;
  if (e >= 64 * N) return;
  const int row = e / N, col = e - row * N;
  float4 acc;
  if (bias) acc = *(const float4*)&bias[col];
  else { acc.x = 0.f; acc.y = 0.f; acc.z = 0.f; acc.w = 0.f; }
  for (int s = 0; s < nsplit; ++s) {
    const float4 p = *(const float4*)&part[((size_t)s * 64 + row) * N + col];
    acc.x += p.x; acc.y += p.y; acc.z += p.z; acc.w += p.w;
  }
  if (relu) {
    acc.x = fmaxf(acc.x, 0.f); acc.y = fmaxf(acc.y, 0.f);
    acc.z = fmaxf(acc.z, 0.f); acc.w = fmaxf(acc.w, 0.f);
  }
  size_t oidx;
  if (!perm) {
    oidx = (size_t)row * N + col;
  } else {
    const int b = row >> 3, h = row & 7;
    oidx = (size_t)(b * 8 + (col >> 9)) * 4096 + h * 512 + (col & 511);
  }
  *(float4*)&out[oidx] = acc;
}

// ---------------- attention 2: 2048 queries vs 8 anchor keys + PV ----------------
__global__ __launch_bounds__(256) void attn2_kernel(const u16* __restrict__ qkv,
                                                    const float* __restrict__ kk,
                                                    const float* __restrict__ onet,
                                                    u16* __restrict__ y) {
  __shared__ float kkl[8][128];
  __shared__ float ovl[8][128];
  const int tid = threadIdx.x;
  const int chunk = blockIdx.x & 7, bh = blockIdx.x >> 3;
  const int b = bh >> 3, h = bh & 7;
  for (int i = tid; i < 1024; i += 256) {
    const int a = i >> 7, d = i & 127;
    kkl[a][d] = kk[(size_t)(b * 8 + a) * 1024 + h * 128 + d];
    ovl[a][d] = onet[(size_t)(b * 8 + a) * 1024 + h * 128 + d];
  }
  __syncthreads();
  const int n = chunk * 256 + tid;
  const u16* qp = qkv + (size_t)(b * 2048 + n) * 3072 + h * 128;
  float dots[8] = {0, 0, 0, 0, 0, 0, 0, 0};
#pragma unroll 4
  for (int dd = 0; dd < 128; dd += 4) {
    const ushort4 q4 = *(const ushort4*)(qp + dd);
    const float q0 = bf2f(q4.x), q1 = bf2f(q4.y), q2 = bf2f(q4.z), q3 = bf2f(q4.w);
#pragma unroll
    for (int a = 0; a < 8; ++a) {
      const float4 k4 = *(const float4*)&kkl[a][dd];
      dots[a] += k4.x * q0 + k4.y * q1 + k4.z * q2 + k4.w * q3;
    }
  }
  const float scale = 0.0883883476483184f;
  float mx = -1e30f;
#pragma unroll
  for (int a = 0; a < 8; ++a) {
    dots[a] *= scale;
    mx = fmaxf(mx, dots[a]);
  }
  float p[8];
  float sum = 0.f;
#pragma unroll
  for (int a = 0; a < 8; ++a) {
    p[a] = __expf(dots[a] - mx);
    sum += p[a];
  }
  const float inv = 1.f / sum;
#pragma unroll
  for (int a = 0; a < 8; ++a) p[a] *= inv;
  u16* yp = y + (size_t)(b * 2048 + n) * 1024 + h * 128;
#pragma unroll 4
  for (int dd = 0; dd < 128; dd += 4) {
    float a0 = 0, a1 = 0, a2 = 0, a3 = 0;
#pragma unroll
    for (int a = 0; a < 8; ++a) {
      const float4 o4 = *(const float4*)&ovl[a][dd];
      a0 += p[a] * o4.x;
      a1 += p[a] * o4.y;
      a2 += p[a] * o4.z;
      a3 += p[a] * o4.w;
    }
    ushort4 o;
    o.x = f2bf(a0);
    o.y = f2bf(a1);
    o.z = f2bf(a2);
    o.w = f2bf(a3);
    *(ushort4*)(yp + dd) = o;
  }
}

extern "C" void kernel_launch(void* const* d_in, const int* in_sizes, int n_in,
                              void* d_out, int out_size, void* d_ws, size_t ws_size,
                              hipStream_t stream) {
  const float* inputs = (const float*)d_in[0];
  const float* ln_g = (const float*)d_in[1];
  const float* ln_b = (const float*)d_in[2];
  const float* q_anchor = (const float*)d_in[3];
  const float* W_qkv = (const float*)d_in[4];
  const float* b_qkv = (const float*)d_in[5];
  const float* W_an = (const float*)d_in[6];
  const float* b_an = (const float*)d_in[7];
  const float* W_n1 = (const float*)d_in[8];
  const float* b_n1 = (const float*)d_in[9];
  const float* W_n2 = (const float*)d_in[10];
  const float* b_n2 = (const float*)d_in[11];
  const float* W_n3 = (const float*)d_in[12];
  const float* b_n3 = (const float*)d_in[13];
  const float* W_k = (const float*)d_in[14];
  const float* b_k = (const float*)d_in[15];
  const float* W_o = (const float*)d_in[16];
  const float* b_o = (const float*)d_in[17];
  float* out = (float*)d_out;

  char* ws = (char*)d_ws;
  u16* qkv = (u16*)(ws);                                   // 16384*3072 bf16 = 96 MB
  u16* xbf = (u16*)(ws + 100663296);                       // 16384*1024 bf16 (x, later y)
  float* S = (float*)(ws + 100663296);                     // attn1 scores 4 MB (overlays dead x)
  float* part = (float*)(ws + 109051904);                  // pv/mlp partials <=8 MB (dead region)
  u16* WqkvT = (u16*)(ws + 134217728);                     // 3072*1024 bf16
  u16* WoT = (u16*)(ws + 140509184);                       // 1024*1024 bf16
  float* att1 = (float*)(ws + 142606336);                  // 64*1024
  float* anp = (float*)(ws + 142868480);                   // 64*4096
  float* h1 = (float*)(ws + 143917056);                    // 64*1024
  float* h2 = (float*)(ws + 144179200);                    // 64*4096
  float* onet = (float*)(ws + 145227776);                  // 64*1024
  float* kkb = (float*)(ws + 145489920);                   // 64*1024

  // 1) LayerNorm -> x bf16
  ln_kernel<<<16384, 256, 0, stream>>>(inputs, ln_g, ln_b, xbf);
  // 2) weight transpose/convert
  transpose_bf16<<<dim3(32, 96), 256, 0, stream>>>(W_qkv, WqkvT, 1024, 3072);
  transpose_bf16<<<dim3(32, 32), 256, 0, stream>>>(W_o, WoT, 1024, 1024);
  // 3) QKV GEMM (256x256 pipelined 32x32x16) -> qkv bf16
  gemm_bf16<0><<<dim3(64, 12), 512, 0, stream>>>(xbf, WqkvT, b_qkv, nullptr, qkv, nullptr,
                                                 16384, 3072, 1024);
  // 4) anchor attention: scores -> softmax -> partial PV -> reduce
  attn1_scores<<<512, 256, 0, stream>>>(qkv, q_anchor, S);
  attn1_softmax<<<512, 256, 0, stream>>>(S);
  attn1_pv<<<512, 256, 0, stream>>>(qkv, S, part);
  mlp_reduce<<<64, 256, 0, stream>>>(part, nullptr, att1, 1024, 16, 0, 0);
  // 5) MLP chain: MFMA split-K GEMMs -> fused reduce(bias/relu/permute)
  mlp_mfma<<<dim3(64, 8), 256, 0, stream>>>(att1, W_an, part, 1024, 4096, 128);
  mlp_reduce<<<256, 256, 0, stream>>>(part, b_an, anp, 4096, 8, 1, 1);
  mlp_mfma<<<dim3(16, 32), 256, 0, stream>>>(anp, W_n1, part, 4096, 1024, 128);
  mlp_reduce<<<64, 256, 0, stream>>>(part, b_n1, h1, 1024, 32, 0, 0);
  mlp_mfma<<<dim3(64, 8), 256, 0, stream>>>(h1, W_n2, part, 1024, 4096, 128);
  mlp_reduce<<<256, 256, 0, stream>>>(part, b_n2, h2, 4096, 8, 1, 0);
  mlp_mfma<<<dim3(16, 32), 256, 0, stream>>>(h2, W_n3, part, 4096, 1024, 128);
  mlp_reduce<<<64, 256, 0, stream>>>(part, b_n3, onet, 1024, 32, 0, 0);
  mlp_mfma<<<dim3(16, 16), 256, 0, stream>>>(onet, W_k, part, 1024, 1024, 64);
  mlp_reduce<<<64, 256, 0, stream>>>(part, b_k, kkb, 1024, 16, 0, 0);
  // 6) query attention over 8 anchors -> y bf16 (reuses xbf buffer)
  attn2_kernel<<<512, 256, 0, stream>>>(qkv, kkb, onet, xbf);
  // 7) output GEMM (256x256 pipelined 32x32x16) + bias + residual -> d_out f32
  gemm_bf16<1><<<dim3(64, 4), 512, 0, stream>>>(xbf, WoT, b_o, inputs, nullptr, out,
                                                16384, 1024, 1024);
}

// Round 5
// 587.052 us; speedup vs baseline: 1.0243x; 1.0243x over previous
//
#include <hip/hip_runtime.h>
#include <cstdint>
#include <cstddef>

typedef unsigned short u16;
typedef __attribute__((ext_vector_type(8))) short short8;
typedef __attribute__((ext_vector_type(4))) float floatx4;
typedef __attribute__((ext_vector_type(16))) float floatx16;

__device__ __forceinline__ u16 f2bf(float f) {
  unsigned u = __float_as_uint(f);
  u += 0x7fffu + ((u >> 16) & 1u);
  return (u16)(u >> 16);
}
__device__ __forceinline__ float bf2f(u16 s) {
  return __uint_as_float(((unsigned)s) << 16);
}

// ---------------- LayerNorm (f32 in) -> bf16 x ----------------
__global__ __launch_bounds__(256) void ln_kernel(const float* __restrict__ x,
                                                 const float* __restrict__ g,
                                                 const float* __restrict__ bta,
                                                 u16* __restrict__ out) {
  const int row = blockIdx.x;
  const int tid = threadIdx.x;
  const float4 v = ((const float4*)(x + (size_t)row * 1024))[tid];
  float s = v.x + v.y + v.z + v.w;
#pragma unroll
  for (int o = 32; o > 0; o >>= 1) s += __shfl_down(s, o);
  __shared__ float red[4], red2[4];
  const int wv = tid >> 6, ln = tid & 63;
  if (ln == 0) red[wv] = s;
  __syncthreads();
  const float mean = (red[0] + red[1] + red[2] + red[3]) * (1.0f / 1024.0f);
  const float dx = v.x - mean, dy = v.y - mean, dz = v.z - mean, dw = v.w - mean;
  float s2 = dx * dx + dy * dy + dz * dz + dw * dw;
#pragma unroll
  for (int o = 32; o > 0; o >>= 1) s2 += __shfl_down(s2, o);
  if (ln == 0) red2[wv] = s2;
  __syncthreads();
  const float var = (red2[0] + red2[1] + red2[2] + red2[3]) * (1.0f / 1024.0f);
  const float rstd = rsqrtf(var + 1e-6f);
  const float4 gg = ((const float4*)g)[tid];
  const float4 bb = ((const float4*)bta)[tid];
  ushort4 o4;
  o4.x = f2bf(dx * rstd * gg.x + bb.x);
  o4.y = f2bf(dy * rstd * gg.y + bb.y);
  o4.z = f2bf(dz * rstd * gg.z + bb.z);
  o4.w = f2bf(dw * rstd * gg.w + bb.w);
  ((ushort4*)(out + (size_t)row * 1024))[tid] = o4;
}

// ---------------- W (KxN f32) -> WT (NxK bf16) ----------------
__global__ __launch_bounds__(256) void transpose_bf16(const float* __restrict__ W,
                                                      u16* __restrict__ WT,
                                                      int K, int N) {
  __shared__ float t[32][33];
  const int kb = blockIdx.x * 32, nb = blockIdx.y * 32;
  const int tx = threadIdx.x & 31, ty = threadIdx.x >> 5;
#pragma unroll
  for (int i = ty; i < 32; i += 8) t[i][tx] = W[(size_t)(kb + i) * N + nb + tx];
  __syncthreads();
#pragma unroll
  for (int i = ty; i < 32; i += 8) WT[(size_t)(nb + i) * K + kb + tx] = f2bf(t[tx][i]);
}

// ================= 256x256 pipelined bf16 MFMA GEMM (32x32x16) =================
// C = A(MxK) * BT(NxK)^T + bias.  512 threads = 8 waves (2M x 4N), BK=64,
// LDS = 2 dbuf x (A 256x64 + B 256x64) bf16 = 128 KiB -> 1 block/CU.
// Round-5: (a) swizzle generalized to f(row)=(row&7)^((row>>3)&7) on BOTH the
// stage source column and the fragment read -> kills the 4-way conflict the
// 32-row x 2-kg read pattern had under strided lane grouping; (b) boundary
// barrier rotated before the register-only P4, and next-tile B0 fragments
// prefetched between barrier and P4 (into the dead B1 register set) so the
// reads execute under P4's matrix-pipe drain. Counted vmcnt(4); 2 barriers/tile.

__device__ __forceinline__ void stageG(const u16* __restrict__ gp, u16* lp, int K) {
  // rows srow and srow+64 of a 128-row half-tile; lane adds 16B at HW level
  __builtin_amdgcn_global_load_lds((const __attribute__((address_space(1))) void*)gp,
                                   (__attribute__((address_space(3))) void*)lp, 16, 0, 0);
  __builtin_amdgcn_global_load_lds((const __attribute__((address_space(1))) void*)(gp + ((size_t)K << 6)),
                                   (__attribute__((address_space(3))) void*)(lp + 4096), 16, 0, 0);
}

// A fragments: 2 row-tiles (32 rows) x 4 k-steps (K=16 each).
// mi=1 is +32 rows -> (row>>3)&7 flips by 4 -> slot ^4 -> u16 offset ^32.
__device__ __forceinline__ void rdA(short8 (&af)[2][4], const u16* sbuf, const int (&ab)[4],
                                    int halfoff) {
#pragma unroll
  for (int mi = 0; mi < 2; ++mi)
#pragma unroll
    for (int ks = 0; ks < 4; ++ks)
      af[mi][ks] = *(const short8*)(sbuf + halfoff + mi * 2048 + (ab[ks] ^ (mi << 5)));
}
// B fragments: 1 col-tile (32 cols) x 4 k-steps
__device__ __forceinline__ void rdB(short8 (&bf)[4], const u16* sbuf, const int (&bb)[4],
                                    int halfoff) {
#pragma unroll
  for (int ks = 0; ks < 4; ++ks)
    bf[ks] = *(const short8*)(sbuf + halfoff + bb[ks]);
}

template <int Q>
__device__ __forceinline__ void mfmaQ(floatx16 (&acc)[4][2], const short8 (&af)[2][4],
                                      const short8 (&bf)[4]) {
#pragma unroll
  for (int ks = 0; ks < 4; ++ks)
#pragma unroll
    for (int mi = 0; mi < 2; ++mi)
      acc[Q][mi] = __builtin_amdgcn_mfma_f32_32x32x16_bf16(af[mi][ks], bf[ks], acc[Q][mi], 0, 0, 0);
}

// One K-tile. Quadrants (0,0)->(0,1)->(1,1)->(1,0) = acc[0..3].
// bfP enters holding B0(t) (prefetched under the previous P4); bfN is scratch:
// B1(t) for P2/P3, then refilled with B0(t+1) after the rotated barrier.
// Stages: pre-P1: A1(t+1); post-P1: B0(t+1); post-alpha: A0(t+2); post-P3: B1(t+2).
// Rotated boundary: vmcnt(4) + barrier BEFORE P4; prefetch hidden under P4.
template <int B_>
__device__ __forceinline__ void gtile(int t, int NT, int K,
                                      u16 (&sA)[2][16384], u16 (&sB)[2][16384],
                                      const u16* gA_lo, const u16* gA_hi,
                                      const u16* gB_lo, const u16* gB_hi,
                                      u16* ldsA_cur, u16* ldsA_alt,
                                      u16* ldsB_cur, u16* ldsB_alt,
                                      const int (&ab)[4], const int (&bb)[4],
                                      floatx16 (&acc)[4][2],
                                      short8 (&afA)[2][4], short8 (&bfP)[4], short8 (&bfN)[4]) {
  // tile start: A0 reads (8); pin so they are older than the B1 reads below
  rdA(afA, sA[B_], ab, 0);
  __builtin_amdgcn_sched_barrier(0);
  if (t + 1 < NT) stageG(gA_hi + ((t + 1) << 6), ldsA_alt + 8192, K);
  rdB(bfN, sB[B_], bb, 8192);  // B1(t)
  // P1: A0 x B0  (prefetched B0 + A0 complete; B1's 4 reads may be outstanding)
  asm volatile("s_waitcnt lgkmcnt(4)" ::: "memory");
  __builtin_amdgcn_sched_barrier(0);
  __builtin_amdgcn_s_setprio(1);
  mfmaQ<0>(acc, afA, bfP);
  __builtin_amdgcn_s_setprio(0);
  if (t + 1 < NT) stageG(gB_lo + ((t + 1) << 6), ldsB_alt, K);
  // P2: A0 x B1
  asm volatile("s_waitcnt lgkmcnt(0)" ::: "memory");
  __builtin_amdgcn_sched_barrier(0);
  __builtin_amdgcn_s_setprio(1);
  mfmaQ<1>(acc, afA, bfN);
  __builtin_amdgcn_s_setprio(0);
  // prefetch A1 into afA (WAR; reads half1, disjoint from post-alpha A0 stage)
  rdA(afA, sA[B_], ab, 8192);
  // alpha: every wave has completed its A0/B0/B1 reads -> current-buffer staging safe
  __builtin_amdgcn_s_barrier();
  if (t + 2 < NT) stageG(gA_lo + ((t + 2) << 6), ldsA_cur, K);
  // P3: A1 x B1
  asm volatile("s_waitcnt lgkmcnt(0)" ::: "memory");
  __builtin_amdgcn_sched_barrier(0);
  __builtin_amdgcn_s_setprio(1);
  mfmaQ<2>(acc, afA, bfN);
  __builtin_amdgcn_s_setprio(0);
  if (t + 2 < NT) stageG(gB_hi + ((t + 2) << 6), ldsB_cur + 8192, K);
  // rotated boundary: publish tile t+1 (keep {A0(t+2),B1(t+2)} in flight);
  // at t+2==NT those stages don't exist, so drain fully (B0(t+1) must land).
  if (t + 2 < NT) {
    asm volatile("s_waitcnt vmcnt(4)" ::: "memory");
  } else {
    asm volatile("s_waitcnt vmcnt(0)" ::: "memory");
  }
  __builtin_amdgcn_s_barrier();
  // prefetch B0(t+1) from the alt buffer into bfN (B1 dead) -> hidden under P4
  if (t + 1 < NT) rdB(bfN, sB[B_ ^ 1], bb, 0);
  __builtin_amdgcn_sched_barrier(0);
  // P4: A1 x B0 (registers only)
  __builtin_amdgcn_s_setprio(1);
  mfmaQ<3>(acc, afA, bfP);
  __builtin_amdgcn_s_setprio(0);
}

template <int EPI>
__global__ __launch_bounds__(512, 2) void gemm_bf16(const u16* __restrict__ A,
                                                    const u16* __restrict__ BT,
                                                    const float* __restrict__ bias,
                                                    const float* __restrict__ extra,
                                                    u16* __restrict__ outB,
                                                    float* __restrict__ outF,
                                                    int M, int N, int K) {
  __shared__ u16 sA[2][16384];
  __shared__ u16 sB[2][16384];
  const int tid = threadIdx.x;
  const int wave = tid >> 6, lane = tid & 63;
  const int m0 = blockIdx.x * 256, n0 = blockIdx.y * 256;
  const int wr = wave >> 2, wc = wave & 3;  // 2x4 wave grid within a quadrant
  const int l31 = lane & 31, l5 = lane >> 5, l7 = lane & 7;
  const int NT = K >> 6;  // requires K % 128 == 0, K >= 192

  // fragment offsets (u16): row*64 + ((kg ^ f(row))<<3), f(row)=(row&7)^((row>>3)&7)
  const int fa = l7 ^ (l31 >> 3);                    // A row = wr*64 (+mi*32) + l31
  const int fb = l7 ^ ((wc * 4 + (l31 >> 3)) & 7);   // B row = wc*32 + l31
  int ab[4], bb[4];
#pragma unroll
  for (int ks = 0; ks < 4; ++ks) {
    const int kg = (ks << 1) + l5;
    ab[ks] = (wr * 64 + l31) * 64 + (((kg ^ fa) & 7) << 3);
    bb[ks] = (wc * 32 + l31) * 64 + (((kg ^ fb) & 7) << 3);
  }
  // staging source pointers (per lane): f(srow) = (lane>>3) ^ wave
  const int srow = wave * 8 + (lane >> 3);
  const int scol = ((lane & 7) ^ (lane >> 3) ^ wave) << 3;
  const u16* gA_lo = A + (size_t)(m0 + srow) * K + scol;
  const u16* gA_hi = A + (size_t)(m0 + 128 + srow) * K + scol;
  const u16* gB_lo = BT + (size_t)(n0 + srow) * K + scol;
  const u16* gB_hi = BT + (size_t)(n0 + 128 + srow) * K + scol;

  floatx16 acc[4][2];
#pragma unroll
  for (int q = 0; q < 4; ++q)
#pragma unroll
    for (int mi = 0; mi < 2; ++mi)
#pragma unroll
      for (int r = 0; r < 16; ++r) acc[q][mi][r] = 0.f;

  // prologue: tile0 fully (8 loads) + A0(1), B1(1) (4 loads) -> vmcnt(4) = tile0 landed
  stageG(gA_lo, &sA[0][0] + wave * 512, K);
  stageG(gA_hi, &sA[0][8192] + wave * 512, K);
  stageG(gB_lo, &sB[0][0] + wave * 512, K);
  stageG(gB_hi, &sB[0][8192] + wave * 512, K);
  stageG(gA_lo + 64, &sA[1][0] + wave * 512, K);
  stageG(gB_hi + 64, &sB[1][8192] + wave * 512, K);
  asm volatile("s_waitcnt vmcnt(4)" ::: "memory");
  __builtin_amdgcn_s_barrier();

  short8 afA[2][4], bfX[4], bfY[4];
  // prefetch B0(0); oldest LGKM ops so P1's lgkmcnt(4) covers them
  rdB(bfX, sB[0], bb, 0);
  __builtin_amdgcn_sched_barrier(0);

  for (int t = 0; t < NT; t += 2) {
    gtile<0>(t, NT, K, sA, sB, gA_lo, gA_hi, gB_lo, gB_hi,
             &sA[0][0] + wave * 512, &sA[1][0] + wave * 512,
             &sB[0][0] + wave * 512, &sB[1][0] + wave * 512, ab, bb, acc, afA, bfX, bfY);
    gtile<1>(t + 1, NT, K, sA, sB, gA_lo, gA_hi, gB_lo, gB_hi,
             &sA[1][0] + wave * 512, &sA[0][0] + wave * 512,
             &sB[1][0] + wave * 512, &sB[0][0] + wave * 512, ab, bb, acc, afA, bfY, bfX);
  }

  // epilogue: 32x32 C/D layout: col = lane&31, row = (reg&3) + 8*(reg>>2) + 4*(lane>>5)
#pragma unroll
  for (int q = 0; q < 4; ++q) {
    const int QM = q >> 1, QN = QM ^ (q & 1);
    const int n = n0 + QN * 128 + wc * 32 + l31;
    const float bs = bias[n];
#pragma unroll
    for (int mi = 0; mi < 2; ++mi) {
      const int mb = m0 + QM * 128 + wr * 64 + mi * 32 + 4 * l5;
#pragma unroll
      for (int reg = 0; reg < 16; ++reg) {
        const int m = mb + (reg & 3) + 8 * (reg >> 2);
        const float v = acc[q][mi][reg] + bs;
        if (EPI == 0)
          outB[(size_t)m * N + n] = f2bf(v);
        else
          outF[(size_t)m * N + n] = v + extra[(size_t)m * N + n];
      }
    }
  }
}

// ---------------- attn1 stage A: scores S[bh][a][n] ----------------
__global__ __launch_bounds__(256) void attn1_scores(const u16* __restrict__ qkv,
                                                    const float* __restrict__ q_anchor,
                                                    float* __restrict__ S) {
  __shared__ float qa[8][128];
  const int tid = threadIdx.x;
  const int chunk = blockIdx.x & 7, bh = blockIdx.x >> 3;
  const int b = bh >> 3, h = bh & 7;
  for (int i = tid; i < 1024; i += 256) qa[i >> 7][i & 127] = q_anchor[h * 1024 + i];
  __syncthreads();
  const float scale = 0.0883883476483184f;
  const int n = chunk * 256 + tid;
  const u16* kp = qkv + (size_t)(b * 2048 + n) * 3072 + 1024 + h * 128;
  float dots[8] = {0, 0, 0, 0, 0, 0, 0, 0};
#pragma unroll 8
  for (int dd = 0; dd < 128; dd += 4) {
    const ushort4 k4 = *(const ushort4*)(kp + dd);
    const float k0 = bf2f(k4.x), k1 = bf2f(k4.y), k2 = bf2f(k4.z), k3 = bf2f(k4.w);
#pragma unroll
    for (int a = 0; a < 8; ++a) {
      const float4 q4 = *(const float4*)&qa[a][dd];
      dots[a] += q4.x * k0 + q4.y * k1 + q4.z * k2 + q4.w * k3;
    }
  }
#pragma unroll
  for (int a = 0; a < 8; ++a) S[((size_t)(bh * 8 + a)) * 2048 + n] = dots[a] * scale;
}

// ---------------- attn1 stage B: row softmax over 2048, in place ----------------
__global__ __launch_bounds__(256) void attn1_softmax(float* __restrict__ S) {
  const int row = blockIdx.x;
  const int tid = threadIdx.x;
  float* Sp = S + (size_t)row * 2048;
  float4 v0 = ((const float4*)Sp)[tid * 2];
  float4 v1 = ((const float4*)Sp)[tid * 2 + 1];
  float mx = fmaxf(fmaxf(fmaxf(v0.x, v0.y), fmaxf(v0.z, v0.w)),
                   fmaxf(fmaxf(v1.x, v1.y), fmaxf(v1.z, v1.w)));
#pragma unroll
  for (int o = 32; o > 0; o >>= 1) mx = fmaxf(mx, __shfl_xor(mx, o));
  __shared__ float red[4];
  const int wv = tid >> 6, ln = tid & 63;
  if (ln == 0) red[wv] = mx;
  __syncthreads();
  mx = fmaxf(fmaxf(red[0], red[1]), fmaxf(red[2], red[3]));
  v0.x = __expf(v0.x - mx); v0.y = __expf(v0.y - mx);
  v0.z = __expf(v0.z - mx); v0.w = __expf(v0.w - mx);
  v1.x = __expf(v1.x - mx); v1.y = __expf(v1.y - mx);
  v1.z = __expf(v1.z - mx); v1.w = __expf(v1.w - mx);
  float sum = v0.x + v0.y + v0.z + v0.w + v1.x + v1.y + v1.z + v1.w;
#pragma unroll
  for (int o = 32; o > 0; o >>= 1) sum += __shfl_xor(sum, o);
  __shared__ float red2[4];
  if (ln == 0) red2[wv] = sum;
  __syncthreads();
  const float inv = 1.f / (red2[0] + red2[1] + red2[2] + red2[3]);
  v0.x *= inv; v0.y *= inv; v0.z *= inv; v0.w *= inv;
  v1.x *= inv; v1.y *= inv; v1.z *= inv; v1.w *= inv;
  ((float4*)Sp)[tid * 2] = v0;
  ((float4*)Sp)[tid * 2 + 1] = v1;
}

// ---------------- attn1 stage C: partial PV -> pvpart[16 splits][64][1024] ----------------
__global__ __launch_bounds__(256) void attn1_pv(const u16* __restrict__ qkv,
                                                const float* __restrict__ S,
                                                float* __restrict__ pvpart) {
  __shared__ float P[8][256];
  const int tid = threadIdx.x;
  const int chunk = blockIdx.x & 7, bh = blockIdx.x >> 3;
  const int b = bh >> 3, h = bh & 7;
  for (int i = tid; i < 2048; i += 256) {
    const int a = i >> 8, n = i & 255;
    P[a][n] = S[((size_t)(bh * 8 + a)) * 2048 + chunk * 256 + n];
  }
  __syncthreads();
  const int d = tid & 127, half = tid >> 7;
  const int nbase = chunk * 256 + half * 128;
  const u16* vp = qkv + (size_t)(b * 2048 + nbase) * 3072 + 2048 + h * 128 + d;
  float acc[8] = {0.f};
  for (int n = 0; n < 128; n += 4) {
    const float v0 = bf2f(vp[(size_t)n * 3072]);
    const float v1 = bf2f(vp[(size_t)(n + 1) * 3072]);
    const float v2 = bf2f(vp[(size_t)(n + 2) * 3072]);
    const float v3 = bf2f(vp[(size_t)(n + 3) * 3072]);
#pragma unroll
    for (int a = 0; a < 8; ++a) {
      const float4 s4 = *(const float4*)&P[a][half * 128 + n];
      acc[a] += s4.x * v0 + s4.y * v1 + s4.z * v2 + s4.w * v3;
    }
  }
  const int split = chunk * 2 + half;
#pragma unroll
  for (int a = 0; a < 8; ++a)
    pvpart[((size_t)split * 64 + bh) * 1024 + a * 128 + d] = acc[a];
}

// ---------------- MLP MFMA GEMM: part[split][64][N] = A[64][Kc] @ W[Kc][N] ----------------
__global__ __launch_bounds__(256) void mlp_mfma(const float* __restrict__ A,
                                                const float* __restrict__ W,
                                                float* __restrict__ part,
                                                int K, int N, int KC) {
  __shared__ float sW[64][33];
  const int tid = threadIdx.x;
  const int lane = tid & 63, wave = tid >> 6;
  const int wm = wave * 16;
  const int n0 = blockIdx.x * 64;
  const int kbeg = blockIdx.y * KC;
  const int l15 = lane & 15, kq8 = (lane >> 4) * 8;
  const int arow = wm + l15;

  floatx4 acc[4];
  const floatx4 zero = {0.f, 0.f, 0.f, 0.f};
#pragma unroll
  for (int j = 0; j < 4; ++j) acc[j] = zero;

  for (int kc = 0; kc < KC; kc += 32) {
    const int kbase = kbeg + kc;
    __syncthreads();
#pragma unroll
    for (int p = 0; p < 8; ++p) {
      const int k = p * 4 + wave;
      sW[lane][k] = W[(size_t)(kbase + k) * N + n0 + lane];
    }
    const float* ap = A + (size_t)arow * K + kbase + kq8;
    const float4 a0 = *(const float4*)ap;
    const float4 a1 = *(const float4*)(ap + 4);
    short8 af;
    af[0] = (short)f2bf(a0.x); af[1] = (short)f2bf(a0.y);
    af[2] = (short)f2bf(a0.z); af[3] = (short)f2bf(a0.w);
    af[4] = (short)f2bf(a1.x); af[5] = (short)f2bf(a1.y);
    af[6] = (short)f2bf(a1.z); af[7] = (short)f2bf(a1.w);
    __syncthreads();
#pragma unroll
    for (int j = 0; j < 4; ++j) {
      const float* wp = &sW[j * 16 + l15][kq8];
      short8 bf;
      bf[0] = (short)f2bf(wp[0]); bf[1] = (short)f2bf(wp[1]);
      bf[2] = (short)f2bf(wp[2]); bf[3] = (short)f2bf(wp[3]);
      bf[4] = (short)f2bf(wp[4]); bf[5] = (short)f2bf(wp[5]);
      bf[6] = (short)f2bf(wp[6]); bf[7] = (short)f2bf(wp[7]);
      acc[j] = __builtin_amdgcn_mfma_f32_16x16x32_bf16(af, bf, acc[j], 0, 0, 0);
    }
  }
  const int q = lane >> 4;
#pragma unroll
  for (int j = 0; j < 4; ++j)
#pragma unroll
    for (int r = 0; r < 4; ++r) {
      const int m = wm + q * 4 + r;
      const int n = n0 + j * 16 + l15;
      part[((size_t)blockIdx.y * 64 + m) * N + n] = acc[j][r];
    }
}

// ---------------- reduce: out = [relu](sum_s part + bias), optional an-permute ----------------
__global__ __launch_bounds__(256) void mlp_reduce(const float* __restrict__ part,
                                                  const float* __restrict__ bias,
                                                  float* __restrict__ out,
                                                  int N, int nsplit, int relu, int perm) {
  const int idx = blockIdx.x * 256 + threadIdx.x;
  const int e = idx * 4;
  if (e >= 64 * N) return;
  const int row = e / N, col = e - row * N;
  float4 acc;
  if (bias) acc = *(const float4*)&bias[col];
  else { acc.x = 0.f; acc.y = 0.f; acc.z = 0.f; acc.w = 0.f; }
  for (int s = 0; s < nsplit; ++s) {
    const float4 p = *(const float4*)&part[((size_t)s * 64 + row) * N + col];
    acc.x += p.x; acc.y += p.y; acc.z += p.z; acc.w += p.w;
  }
  if (relu) {
    acc.x = fmaxf(acc.x, 0.f); acc.y = fmaxf(acc.y, 0.f);
    acc.z = fmaxf(acc.z, 0.f); acc.w = fmaxf(acc.w, 0.f);
  }
  size_t oidx;
  if (!perm) {
    oidx = (size_t)row * N + col;
  } else {
    const int b = row >> 3, h = row & 7;
    oidx = (size_t)(b * 8 + (col >> 9)) * 4096 + h * 512 + (col & 511);
  }
  *(float4*)&out[oidx] = acc;
}

// ---------------- attention 2: 2048 queries vs 8 anchor keys + PV ----------------
__global__ __launch_bounds__(256) void attn2_kernel(const u16* __restrict__ qkv,
                                                    const float* __restrict__ kk,
                                                    const float* __restrict__ onet,
                                                    u16* __restrict__ y) {
  __shared__ float kkl[8][128];
  __shared__ float ovl[8][128];
  const int tid = threadIdx.x;
  const int chunk = blockIdx.x & 7, bh = blockIdx.x >> 3;
  const int b = bh >> 3, h = bh & 7;
  for (int i = tid; i < 1024; i += 256) {
    const int a = i >> 7, d = i & 127;
    kkl[a][d] = kk[(size_t)(b * 8 + a) * 1024 + h * 128 + d];
    ovl[a][d] = onet[(size_t)(b * 8 + a) * 1024 + h * 128 + d];
  }
  __syncthreads();
  const int n = chunk * 256 + tid;
  const u16* qp = qkv + (size_t)(b * 2048 + n) * 3072 + h * 128;
  float dots[8] = {0, 0, 0, 0, 0, 0, 0, 0};
#pragma unroll 4
  for (int dd = 0; dd < 128; dd += 4) {
    const ushort4 q4 = *(const ushort4*)(qp + dd);
    const float q0 = bf2f(q4.x), q1 = bf2f(q4.y), q2 = bf2f(q4.z), q3 = bf2f(q4.w);
#pragma unroll
    for (int a = 0; a < 8; ++a) {
      const float4 k4 = *(const float4*)&kkl[a][dd];
      dots[a] += k4.x * q0 + k4.y * q1 + k4.z * q2 + k4.w * q3;
    }
  }
  const float scale = 0.0883883476483184f;
  float mx = -1e30f;
#pragma unroll
  for (int a = 0; a < 8; ++a) {
    dots[a] *= scale;
    mx = fmaxf(mx, dots[a]);
  }
  float p[8];
  float sum = 0.f;
#pragma unroll
  for (int a = 0; a < 8; ++a) {
    p[a] = __expf(dots[a] - mx);
    sum += p[a];
  }
  const float inv = 1.f / sum;
#pragma unroll
  for (int a = 0; a < 8; ++a) p[a] *= inv;
  u16* yp = y + (size_t)(b * 2048 + n) * 1024 + h * 128;
#pragma unroll 4
  for (int dd = 0; dd < 128; dd += 4) {
    float a0 = 0, a1 = 0, a2 = 0, a3 = 0;
#pragma unroll
    for (int a = 0; a < 8; ++a) {
      const float4 o4 = *(const float4*)&ovl[a][dd];
      a0 += p[a] * o4.x;
      a1 += p[a] * o4.y;
      a2 += p[a] * o4.z;
      a3 += p[a] * o4.w;
    }
    ushort4 o;
    o.x = f2bf(a0);
    o.y = f2bf(a1);
    o.z = f2bf(a2);
    o.w = f2bf(a3);
    *(ushort4*)(yp + dd) = o;
  }
}

extern "C" void kernel_launch(void* const* d_in, const int* in_sizes, int n_in,
                              void* d_out, int out_size, void* d_ws, size_t ws_size,
                              hipStream_t stream) {
  const float* inputs = (const float*)d_in[0];
  const float* ln_g = (const float*)d_in[1];
  const float* ln_b = (const float*)d_in[2];
  const float* q_anchor = (const float*)d_in[3];
  const float* W_qkv = (const float*)d_in[4];
  const float* b_qkv = (const float*)d_in[5];
  const float* W_an = (const float*)d_in[6];
  const float* b_an = (const float*)d_in[7];
  const float* W_n1 = (const float*)d_in[8];
  const float* b_n1 = (const float*)d_in[9];
  const float* W_n2 = (const float*)d_in[10];
  const float* b_n2 = (const float*)d_in[11];
  const float* W_n3 = (const float*)d_in[12];
  const float* b_n3 = (const float*)d_in[13];
  const float* W_k = (const float*)d_in[14];
  const float* b_k = (const float*)d_in[15];
  const float* W_o = (const float*)d_in[16];
  const float* b_o = (const float*)d_in[17];
  float* out = (float*)d_out;

  char* ws = (char*)d_ws;
  u16* qkv = (u16*)(ws);                                   // 16384*3072 bf16 = 96 MB
  u16* xbf = (u16*)(ws + 100663296);                       // 16384*1024 bf16 (x, later y)
  float* S = (float*)(ws + 100663296);                     // attn1 scores 4 MB (overlays dead x)
  float* part = (float*)(ws + 109051904);                  // pv/mlp partials <=8 MB (dead region)
  u16* WqkvT = (u16*)(ws + 134217728);                     // 3072*1024 bf16
  u16* WoT = (u16*)(ws + 140509184);                       // 1024*1024 bf16
  float* att1 = (float*)(ws + 142606336);                  // 64*1024
  float* anp = (float*)(ws + 142868480);                   // 64*4096
  float* h1 = (float*)(ws + 143917056);                    // 64*1024
  float* h2 = (float*)(ws + 144179200);                    // 64*4096
  float* onet = (float*)(ws + 145227776);                  // 64*1024
  float* kkb = (float*)(ws + 145489920);                   // 64*1024

  // 1) LayerNorm -> x bf16
  ln_kernel<<<16384, 256, 0, stream>>>(inputs, ln_g, ln_b, xbf);
  // 2) weight transpose/convert
  transpose_bf16<<<dim3(32, 96), 256, 0, stream>>>(W_qkv, WqkvT, 1024, 3072);
  transpose_bf16<<<dim3(32, 32), 256, 0, stream>>>(W_o, WoT, 1024, 1024);
  // 3) QKV GEMM (256x256 pipelined 32x32x16) -> qkv bf16
  gemm_bf16<0><<<dim3(64, 12), 512, 0, stream>>>(xbf, WqkvT, b_qkv, nullptr, qkv, nullptr,
                                                 16384, 3072, 1024);
  // 4) anchor attention: scores -> softmax -> partial PV -> reduce
  attn1_scores<<<512, 256, 0, stream>>>(qkv, q_anchor, S);
  attn1_softmax<<<512, 256, 0, stream>>>(S);
  attn1_pv<<<512, 256, 0, stream>>>(qkv, S, part);
  mlp_reduce<<<64, 256, 0, stream>>>(part, nullptr, att1, 1024, 16, 0, 0);
  // 5) MLP chain: MFMA split-K GEMMs -> fused reduce(bias/relu/permute)
  mlp_mfma<<<dim3(64, 8), 256, 0, stream>>>(att1, W_an, part, 1024, 4096, 128);
  mlp_reduce<<<256, 256, 0, stream>>>(part, b_an, anp, 4096, 8, 1, 1);
  mlp_mfma<<<dim3(16, 32), 256, 0, stream>>>(anp, W_n1, part, 4096, 1024, 128);
  mlp_reduce<<<64, 256, 0, stream>>>(part, b_n1, h1, 1024, 32, 0, 0);
  mlp_mfma<<<dim3(64, 8), 256, 0, stream>>>(h1, W_n2, part, 1024, 4096, 128);
  mlp_reduce<<<256, 256, 0, stream>>>(part, b_n2, h2, 4096, 8, 1, 0);
  mlp_mfma<<<dim3(16, 32), 256, 0, stream>>>(h2, W_n3, part, 4096, 1024, 128);
  mlp_reduce<<<64, 256, 0, stream>>>(part, b_n3, onet, 1024, 32, 0, 0);
  mlp_mfma<<<dim3(16, 16), 256, 0, stream>>>(onet, W_k, part, 1024, 1024, 64);
  mlp_reduce<<<64, 256, 0, stream>>>(part, b_k, kkb, 1024, 16, 0, 0);
  // 6) query attention over 8 anchors -> y bf16 (reuses xbf buffer)
  attn2_kernel<<<512, 256, 0, stream>>>(qkv, kkb, onet, xbf);
  // 7) output GEMM (256x256 pipelined 32x32x16) + bias + residual -> d_out f32
  gemm_bf16<1><<<dim3(64, 4), 512, 0, stream>>>(xbf, WoT, b_o, inputs, nullptr, out,
                                                16384, 1024, 1024);
}

// Round 6
// 578.060 us; speedup vs baseline: 1.0403x; 1.0156x over previous
//
#include <hip/hip_runtime.h>
#include <cstdint>
#include <cstddef>

typedef unsigned short u16;
typedef __attribute__((ext_vector_type(8))) short short8;
typedef __attribute__((ext_vector_type(4))) float floatx4;
typedef __attribute__((ext_vector_type(16))) float floatx16;

__device__ __forceinline__ u16 f2bf(float f) {
  unsigned u = __float_as_uint(f);
  u += 0x7fffu + ((u >> 16) & 1u);
  return (u16)(u >> 16);
}
__device__ __forceinline__ float bf2f(u16 s) {
  return __uint_as_float(((unsigned)s) << 16);
}

// ---------------- LayerNorm (f32 in) -> bf16 x ----------------
__global__ __launch_bounds__(256) void ln_kernel(const float* __restrict__ x,
                                                 const float* __restrict__ g,
                                                 const float* __restrict__ bta,
                                                 u16* __restrict__ out) {
  const int row = blockIdx.x;
  const int tid = threadIdx.x;
  const float4 v = ((const float4*)(x + (size_t)row * 1024))[tid];
  float s = v.x + v.y + v.z + v.w;
#pragma unroll
  for (int o = 32; o > 0; o >>= 1) s += __shfl_down(s, o);
  __shared__ float red[4], red2[4];
  const int wv = tid >> 6, ln = tid & 63;
  if (ln == 0) red[wv] = s;
  __syncthreads();
  const float mean = (red[0] + red[1] + red[2] + red[3]) * (1.0f / 1024.0f);
  const float dx = v.x - mean, dy = v.y - mean, dz = v.z - mean, dw = v.w - mean;
  float s2 = dx * dx + dy * dy + dz * dz + dw * dw;
#pragma unroll
  for (int o = 32; o > 0; o >>= 1) s2 += __shfl_down(s2, o);
  if (ln == 0) red2[wv] = s2;
  __syncthreads();
  const float var = (red2[0] + red2[1] + red2[2] + red2[3]) * (1.0f / 1024.0f);
  const float rstd = rsqrtf(var + 1e-6f);
  const float4 gg = ((const float4*)g)[tid];
  const float4 bb = ((const float4*)bta)[tid];
  ushort4 o4;
  o4.x = f2bf(dx * rstd * gg.x + bb.x);
  o4.y = f2bf(dy * rstd * gg.y + bb.y);
  o4.z = f2bf(dz * rstd * gg.z + bb.z);
  o4.w = f2bf(dw * rstd * gg.w + bb.w);
  ((ushort4*)(out + (size_t)row * 1024))[tid] = o4;
}

// ---------------- both weight transposes in one launch ----------------
// grid (32, 96+32): y<96 -> W_qkv (1024x3072); else W_o (1024x1024). K=1024 both.
__global__ __launch_bounds__(256) void transpose2_bf16(const float* __restrict__ Wq,
                                                       u16* __restrict__ WqT,
                                                       const float* __restrict__ Wo,
                                                       u16* __restrict__ WoT) {
  __shared__ float t[32][33];
  const float* W;
  u16* WT;
  int N, yb;
  if (blockIdx.y < 96) { W = Wq; WT = WqT; N = 3072; yb = blockIdx.y; }
  else { W = Wo; WT = WoT; N = 1024; yb = blockIdx.y - 96; }
  const int kb = blockIdx.x * 32, nb = yb * 32;
  const int tx = threadIdx.x & 31, ty = threadIdx.x >> 5;
#pragma unroll
  for (int i = ty; i < 32; i += 8) t[i][tx] = W[(size_t)(kb + i) * N + nb + tx];
  __syncthreads();
#pragma unroll
  for (int i = ty; i < 32; i += 8) WT[(size_t)(nb + i) * 1024 + kb + tx] = f2bf(t[tx][i]);
}

// ---------------- init: zero att1; pre-fill MLP outputs with bias ----------------
// float4 segments: att1 16384 | anp 65536 | h1 16384 | h2 65536 | onet 16384 | kkb 16384
__global__ __launch_bounds__(256) void init_bufs(const float* __restrict__ b_an,
                                                 const float* __restrict__ b_n1,
                                                 const float* __restrict__ b_n2,
                                                 const float* __restrict__ b_n3,
                                                 const float* __restrict__ b_k,
                                                 float* __restrict__ att1,
                                                 float* __restrict__ anp,
                                                 float* __restrict__ h1,
                                                 float* __restrict__ h2,
                                                 float* __restrict__ onet,
                                                 float* __restrict__ kkb) {
  const int i = blockIdx.x * 256 + threadIdx.x;
  if (i < 16384) {
    float4 z; z.x = 0.f; z.y = 0.f; z.z = 0.f; z.w = 0.f;
    ((float4*)att1)[i] = z;
  } else if (i < 81920) {
    const int j = i - 16384;
    ((float4*)anp)[j] = ((const float4*)b_an)[j & 1023];
  } else if (i < 98304) {
    const int j = i - 81920;
    ((float4*)h1)[j] = ((const float4*)b_n1)[j & 255];
  } else if (i < 163840) {
    const int j = i - 98304;
    ((float4*)h2)[j] = ((const float4*)b_n2)[j & 1023];
  } else if (i < 180224) {
    const int j = i - 163840;
    ((float4*)onet)[j] = ((const float4*)b_n3)[j & 255];
  } else {
    const int j = i - 180224;
    ((float4*)kkb)[j] = ((const float4*)b_k)[j & 255];
  }
}

// ================= 256x256 pipelined bf16 MFMA GEMM (32x32x16) =================
// (unchanged from round 5: conflict-free dual-side swizzle, rotated boundary,
//  counted vmcnt(4), 2 barriers/tile)

__device__ __forceinline__ void stageG(const u16* __restrict__ gp, u16* lp, int K) {
  __builtin_amdgcn_global_load_lds((const __attribute__((address_space(1))) void*)gp,
                                   (__attribute__((address_space(3))) void*)lp, 16, 0, 0);
  __builtin_amdgcn_global_load_lds((const __attribute__((address_space(1))) void*)(gp + ((size_t)K << 6)),
                                   (__attribute__((address_space(3))) void*)(lp + 4096), 16, 0, 0);
}

__device__ __forceinline__ void rdA(short8 (&af)[2][4], const u16* sbuf, const int (&ab)[4],
                                    int halfoff) {
#pragma unroll
  for (int mi = 0; mi < 2; ++mi)
#pragma unroll
    for (int ks = 0; ks < 4; ++ks)
      af[mi][ks] = *(const short8*)(sbuf + halfoff + mi * 2048 + (ab[ks] ^ (mi << 5)));
}
__device__ __forceinline__ void rdB(short8 (&bf)[4], const u16* sbuf, const int (&bb)[4],
                                    int halfoff) {
#pragma unroll
  for (int ks = 0; ks < 4; ++ks)
    bf[ks] = *(const short8*)(sbuf + halfoff + bb[ks]);
}

template <int Q>
__device__ __forceinline__ void mfmaQ(floatx16 (&acc)[4][2], const short8 (&af)[2][4],
                                      const short8 (&bf)[4]) {
#pragma unroll
  for (int ks = 0; ks < 4; ++ks)
#pragma unroll
    for (int mi = 0; mi < 2; ++mi)
      acc[Q][mi] = __builtin_amdgcn_mfma_f32_32x32x16_bf16(af[mi][ks], bf[ks], acc[Q][mi], 0, 0, 0);
}

template <int B_>
__device__ __forceinline__ void gtile(int t, int NT, int K,
                                      u16 (&sA)[2][16384], u16 (&sB)[2][16384],
                                      const u16* gA_lo, const u16* gA_hi,
                                      const u16* gB_lo, const u16* gB_hi,
                                      u16* ldsA_cur, u16* ldsA_alt,
                                      u16* ldsB_cur, u16* ldsB_alt,
                                      const int (&ab)[4], const int (&bb)[4],
                                      floatx16 (&acc)[4][2],
                                      short8 (&afA)[2][4], short8 (&bfP)[4], short8 (&bfN)[4]) {
  rdA(afA, sA[B_], ab, 0);
  __builtin_amdgcn_sched_barrier(0);
  if (t + 1 < NT) stageG(gA_hi + ((t + 1) << 6), ldsA_alt + 8192, K);
  rdB(bfN, sB[B_], bb, 8192);  // B1(t)
  asm volatile("s_waitcnt lgkmcnt(4)" ::: "memory");
  __builtin_amdgcn_sched_barrier(0);
  __builtin_amdgcn_s_setprio(1);
  mfmaQ<0>(acc, afA, bfP);
  __builtin_amdgcn_s_setprio(0);
  if (t + 1 < NT) stageG(gB_lo + ((t + 1) << 6), ldsB_alt, K);
  asm volatile("s_waitcnt lgkmcnt(0)" ::: "memory");
  __builtin_amdgcn_sched_barrier(0);
  __builtin_amdgcn_s_setprio(1);
  mfmaQ<1>(acc, afA, bfN);
  __builtin_amdgcn_s_setprio(0);
  rdA(afA, sA[B_], ab, 8192);
  __builtin_amdgcn_s_barrier();
  if (t + 2 < NT) stageG(gA_lo + ((t + 2) << 6), ldsA_cur, K);
  asm volatile("s_waitcnt lgkmcnt(0)" ::: "memory");
  __builtin_amdgcn_sched_barrier(0);
  __builtin_amdgcn_s_setprio(1);
  mfmaQ<2>(acc, afA, bfN);
  __builtin_amdgcn_s_setprio(0);
  if (t + 2 < NT) stageG(gB_hi + ((t + 2) << 6), ldsB_cur + 8192, K);
  if (t + 2 < NT) {
    asm volatile("s_waitcnt vmcnt(4)" ::: "memory");
  } else {
    asm volatile("s_waitcnt vmcnt(0)" ::: "memory");
  }
  __builtin_amdgcn_s_barrier();
  if (t + 1 < NT) rdB(bfN, sB[B_ ^ 1], bb, 0);
  __builtin_amdgcn_sched_barrier(0);
  __builtin_amdgcn_s_setprio(1);
  mfmaQ<3>(acc, afA, bfP);
  __builtin_amdgcn_s_setprio(0);
}

template <int EPI>
__global__ __launch_bounds__(512, 2) void gemm_bf16(const u16* __restrict__ A,
                                                    const u16* __restrict__ BT,
                                                    const float* __restrict__ bias,
                                                    const float* __restrict__ extra,
                                                    u16* __restrict__ outB,
                                                    float* __restrict__ outF,
                                                    int M, int N, int K) {
  __shared__ u16 sA[2][16384];
  __shared__ u16 sB[2][16384];
  const int tid = threadIdx.x;
  const int wave = tid >> 6, lane = tid & 63;
  const int m0 = blockIdx.x * 256, n0 = blockIdx.y * 256;
  const int wr = wave >> 2, wc = wave & 3;
  const int l31 = lane & 31, l5 = lane >> 5, l7 = lane & 7;
  const int NT = K >> 6;

  const int fa = l7 ^ (l31 >> 3);
  const int fb = l7 ^ ((wc * 4 + (l31 >> 3)) & 7);
  int ab[4], bb[4];
#pragma unroll
  for (int ks = 0; ks < 4; ++ks) {
    const int kg = (ks << 1) + l5;
    ab[ks] = (wr * 64 + l31) * 64 + (((kg ^ fa) & 7) << 3);
    bb[ks] = (wc * 32 + l31) * 64 + (((kg ^ fb) & 7) << 3);
  }
  const int srow = wave * 8 + (lane >> 3);
  const int scol = ((lane & 7) ^ (lane >> 3) ^ wave) << 3;
  const u16* gA_lo = A + (size_t)(m0 + srow) * K + scol;
  const u16* gA_hi = A + (size_t)(m0 + 128 + srow) * K + scol;
  const u16* gB_lo = BT + (size_t)(n0 + srow) * K + scol;
  const u16* gB_hi = BT + (size_t)(n0 + 128 + srow) * K + scol;

  floatx16 acc[4][2];
#pragma unroll
  for (int q = 0; q < 4; ++q)
#pragma unroll
    for (int mi = 0; mi < 2; ++mi)
#pragma unroll
      for (int r = 0; r < 16; ++r) acc[q][mi][r] = 0.f;

  stageG(gA_lo, &sA[0][0] + wave * 512, K);
  stageG(gA_hi, &sA[0][8192] + wave * 512, K);
  stageG(gB_lo, &sB[0][0] + wave * 512, K);
  stageG(gB_hi, &sB[0][8192] + wave * 512, K);
  stageG(gA_lo + 64, &sA[1][0] + wave * 512, K);
  stageG(gB_hi + 64, &sB[1][8192] + wave * 512, K);
  asm volatile("s_waitcnt vmcnt(4)" ::: "memory");
  __builtin_amdgcn_s_barrier();

  short8 afA[2][4], bfX[4], bfY[4];
  rdB(bfX, sB[0], bb, 0);
  __builtin_amdgcn_sched_barrier(0);

  for (int t = 0; t < NT; t += 2) {
    gtile<0>(t, NT, K, sA, sB, gA_lo, gA_hi, gB_lo, gB_hi,
             &sA[0][0] + wave * 512, &sA[1][0] + wave * 512,
             &sB[0][0] + wave * 512, &sB[1][0] + wave * 512, ab, bb, acc, afA, bfX, bfY);
    gtile<1>(t + 1, NT, K, sA, sB, gA_lo, gA_hi, gB_lo, gB_hi,
             &sA[1][0] + wave * 512, &sA[0][0] + wave * 512,
             &sB[1][0] + wave * 512, &sB[0][0] + wave * 512, ab, bb, acc, afA, bfY, bfX);
  }

#pragma unroll
  for (int q = 0; q < 4; ++q) {
    const int QM = q >> 1, QN = QM ^ (q & 1);
    const int n = n0 + QN * 128 + wc * 32 + l31;
    const float bs = bias[n];
#pragma unroll
    for (int mi = 0; mi < 2; ++mi) {
      const int mb = m0 + QM * 128 + wr * 64 + mi * 32 + 4 * l5;
#pragma unroll
      for (int reg = 0; reg < 16; ++reg) {
        const int m = mb + (reg & 3) + 8 * (reg >> 2);
        const float v = acc[q][mi][reg] + bs;
        if (EPI == 0)
          outB[(size_t)m * N + n] = f2bf(v);
        else
          outF[(size_t)m * N + n] = v + extra[(size_t)m * N + n];
      }
    }
  }
}

// ---------------- attn1 stage A: scores S[bh][a][n] ----------------
__global__ __launch_bounds__(256) void attn1_scores(const u16* __restrict__ qkv,
                                                    const float* __restrict__ q_anchor,
                                                    float* __restrict__ S) {
  __shared__ float qa[8][128];
  const int tid = threadIdx.x;
  const int chunk = blockIdx.x & 7, bh = blockIdx.x >> 3;
  const int b = bh >> 3, h = bh & 7;
  for (int i = tid; i < 1024; i += 256) qa[i >> 7][i & 127] = q_anchor[h * 1024 + i];
  __syncthreads();
  const float scale = 0.0883883476483184f;
  const int n = chunk * 256 + tid;
  const u16* kp = qkv + (size_t)(b * 2048 + n) * 3072 + 1024 + h * 128;
  float dots[8] = {0, 0, 0, 0, 0, 0, 0, 0};
#pragma unroll 8
  for (int dd = 0; dd < 128; dd += 4) {
    const ushort4 k4 = *(const ushort4*)(kp + dd);
    const float k0 = bf2f(k4.x), k1 = bf2f(k4.y), k2 = bf2f(k4.z), k3 = bf2f(k4.w);
#pragma unroll
    for (int a = 0; a < 8; ++a) {
      const float4 q4 = *(const float4*)&qa[a][dd];
      dots[a] += q4.x * k0 + q4.y * k1 + q4.z * k2 + q4.w * k3;
    }
  }
#pragma unroll
  for (int a = 0; a < 8; ++a) S[((size_t)(bh * 8 + a)) * 2048 + n] = dots[a] * scale;
}

// ---------------- attn1 stage B: row softmax over 2048, in place ----------------
__global__ __launch_bounds__(256) void attn1_softmax(float* __restrict__ S) {
  const int row = blockIdx.x;
  const int tid = threadIdx.x;
  float* Sp = S + (size_t)row * 2048;
  float4 v0 = ((const float4*)Sp)[tid * 2];
  float4 v1 = ((const float4*)Sp)[tid * 2 + 1];
  float mx = fmaxf(fmaxf(fmaxf(v0.x, v0.y), fmaxf(v0.z, v0.w)),
                   fmaxf(fmaxf(v1.x, v1.y), fmaxf(v1.z, v1.w)));
#pragma unroll
  for (int o = 32; o > 0; o >>= 1) mx = fmaxf(mx, __shfl_xor(mx, o));
  __shared__ float red[4];
  const int wv = tid >> 6, ln = tid & 63;
  if (ln == 0) red[wv] = mx;
  __syncthreads();
  mx = fmaxf(fmaxf(red[0], red[1]), fmaxf(red[2], red[3]));
  v0.x = __expf(v0.x - mx); v0.y = __expf(v0.y - mx);
  v0.z = __expf(v0.z - mx); v0.w = __expf(v0.w - mx);
  v1.x = __expf(v1.x - mx); v1.y = __expf(v1.y - mx);
  v1.z = __expf(v1.z - mx); v1.w = __expf(v1.w - mx);
  float sum = v0.x + v0.y + v0.z + v0.w + v1.x + v1.y + v1.z + v1.w;
#pragma unroll
  for (int o = 32; o > 0; o >>= 1) sum += __shfl_xor(sum, o);
  __shared__ float red2[4];
  if (ln == 0) red2[wv] = sum;
  __syncthreads();
  const float inv = 1.f / (red2[0] + red2[1] + red2[2] + red2[3]);
  v0.x *= inv; v0.y *= inv; v0.z *= inv; v0.w *= inv;
  v1.x *= inv; v1.y *= inv; v1.z *= inv; v1.w *= inv;
  ((float4*)Sp)[tid * 2] = v0;
  ((float4*)Sp)[tid * 2 + 1] = v1;
}

// ---------------- attn1 stage C: partial PV, atomic-reduced into att1 ----------------
__global__ __launch_bounds__(256) void attn1_pv(const u16* __restrict__ qkv,
                                                const float* __restrict__ S,
                                                float* __restrict__ att1) {
  __shared__ float P[8][256];
  const int tid = threadIdx.x;
  const int chunk = blockIdx.x & 7, bh = blockIdx.x >> 3;
  const int b = bh >> 3, h = bh & 7;
  for (int i = tid; i < 2048; i += 256) {
    const int a = i >> 8, n = i & 255;
    P[a][n] = S[((size_t)(bh * 8 + a)) * 2048 + chunk * 256 + n];
  }
  __syncthreads();
  const int d = tid & 127, half = tid >> 7;
  const int nbase = chunk * 256 + half * 128;
  const u16* vp = qkv + (size_t)(b * 2048 + nbase) * 3072 + 2048 + h * 128 + d;
  float acc[8] = {0.f};
  for (int n = 0; n < 128; n += 4) {
    const float v0 = bf2f(vp[(size_t)n * 3072]);
    const float v1 = bf2f(vp[(size_t)(n + 1) * 3072]);
    const float v2 = bf2f(vp[(size_t)(n + 2) * 3072]);
    const float v3 = bf2f(vp[(size_t)(n + 3) * 3072]);
#pragma unroll
    for (int a = 0; a < 8; ++a) {
      const float4 s4 = *(const float4*)&P[a][half * 128 + n];
      acc[a] += s4.x * v0 + s4.y * v1 + s4.z * v2 + s4.w * v3;
    }
  }
#pragma unroll
  for (int a = 0; a < 8; ++a)
    atomicAdd(&att1[(size_t)bh * 1024 + a * 128 + d], acc[a]);
}

// ---------------- MLP MFMA GEMM with fused epilogue ----------------
// outp pre-initialized with bias; split-K partials atomicAdd'ed in.
// AMODE: 0 = A plain; 1 = relu(A); 2 = relu(A) with an-permute indexing
// (A'[r][c] = relu(raw[(r>>3)*8 + (c>>9)][(r&7)*512 + (c&511)])).
template <int AMODE>
__global__ __launch_bounds__(256) void mlp_mfma(const float* __restrict__ A,
                                                const float* __restrict__ W,
                                                float* __restrict__ outp,
                                                int K, int N, int KC) {
  __shared__ float sW[64][33];
  const int tid = threadIdx.x;
  const int lane = tid & 63, wave = tid >> 6;
  const int wm = wave * 16;
  const int n0 = blockIdx.x * 64;
  const int kbeg = blockIdx.y * KC;
  const int l15 = lane & 15, kq8 = (lane >> 4) * 8;
  const int arow = wm + l15;

  floatx4 acc[4];
  const floatx4 zero = {0.f, 0.f, 0.f, 0.f};
#pragma unroll
  for (int j = 0; j < 4; ++j) acc[j] = zero;

  for (int kc = 0; kc < KC; kc += 32) {
    const int kbase = kbeg + kc;
    __syncthreads();
#pragma unroll
    for (int p = 0; p < 8; ++p) {
      const int k = p * 4 + wave;
      sW[lane][k] = W[(size_t)(kbase + k) * N + n0 + lane];
    }
    const float* ap;
    if (AMODE == 2) {
      const int k = kbase + kq8;
      ap = A + (size_t)(arow >> 3) * 32768 + (size_t)(k >> 9) * 4096 + (arow & 7) * 512 + (k & 511);
    } else {
      ap = A + (size_t)arow * K + kbase + kq8;
    }
    float4 a0 = *(const float4*)ap;
    float4 a1 = *(const float4*)(ap + 4);
    if (AMODE >= 1) {
      a0.x = fmaxf(a0.x, 0.f); a0.y = fmaxf(a0.y, 0.f);
      a0.z = fmaxf(a0.z, 0.f); a0.w = fmaxf(a0.w, 0.f);
      a1.x = fmaxf(a1.x, 0.f); a1.y = fmaxf(a1.y, 0.f);
      a1.z = fmaxf(a1.z, 0.f); a1.w = fmaxf(a1.w, 0.f);
    }
    short8 af;
    af[0] = (short)f2bf(a0.x); af[1] = (short)f2bf(a0.y);
    af[2] = (short)f2bf(a0.z); af[3] = (short)f2bf(a0.w);
    af[4] = (short)f2bf(a1.x); af[5] = (short)f2bf(a1.y);
    af[6] = (short)f2bf(a1.z); af[7] = (short)f2bf(a1.w);
    __syncthreads();
#pragma unroll
    for (int j = 0; j < 4; ++j) {
      const float* wp = &sW[j * 16 + l15][kq8];
      short8 bf;
      bf[0] = (short)f2bf(wp[0]); bf[1] = (short)f2bf(wp[1]);
      bf[2] = (short)f2bf(wp[2]); bf[3] = (short)f2bf(wp[3]);
      bf[4] = (short)f2bf(wp[4]); bf[5] = (short)f2bf(wp[5]);
      bf[6] = (short)f2bf(wp[6]); bf[7] = (short)f2bf(wp[7]);
      acc[j] = __builtin_amdgcn_mfma_f32_16x16x32_bf16(af, bf, acc[j], 0, 0, 0);
    }
  }
  const int q = lane >> 4;
#pragma unroll
  for (int j = 0; j < 4; ++j)
#pragma unroll
    for (int r = 0; r < 4; ++r) {
      const int m = wm + q * 4 + r;
      const int n = n0 + j * 16 + l15;
      atomicAdd(&outp[(size_t)m * N + n], acc[j][r]);
    }
}

// ---------------- attention 2: 2048 queries vs 8 anchor keys + PV ----------------
__global__ __launch_bounds__(256) void attn2_kernel(const u16* __restrict__ qkv,
                                                    const float* __restrict__ kk,
                                                    const float* __restrict__ onet,
                                                    u16* __restrict__ y) {
  __shared__ float kkl[8][128];
  __shared__ float ovl[8][128];
  const int tid = threadIdx.x;
  const int chunk = blockIdx.x & 7, bh = blockIdx.x >> 3;
  const int b = bh >> 3, h = bh & 7;
  for (int i = tid; i < 1024; i += 256) {
    const int a = i >> 7, d = i & 127;
    kkl[a][d] = kk[(size_t)(b * 8 + a) * 1024 + h * 128 + d];
    ovl[a][d] = onet[(size_t)(b * 8 + a) * 1024 + h * 128 + d];
  }
  __syncthreads();
  const int n = chunk * 256 + tid;
  const u16* qp = qkv + (size_t)(b * 2048 + n) * 3072 + h * 128;
  float dots[8] = {0, 0, 0, 0, 0, 0, 0, 0};
#pragma unroll 4
  for (int dd = 0; dd < 128; dd += 4) {
    const ushort4 q4 = *(const ushort4*)(qp + dd);
    const float q0 = bf2f(q4.x), q1 = bf2f(q4.y), q2 = bf2f(q4.z), q3 = bf2f(q4.w);
#pragma unroll
    for (int a = 0; a < 8; ++a) {
      const float4 k4 = *(const float4*)&kkl[a][dd];
      dots[a] += k4.x * q0 + k4.y * q1 + k4.z * q2 + k4.w * q3;
    }
  }
  const float scale = 0.0883883476483184f;
  float mx = -1e30f;
#pragma unroll
  for (int a = 0; a < 8; ++a) {
    dots[a] *= scale;
    mx = fmaxf(mx, dots[a]);
  }
  float p[8];
  float sum = 0.f;
#pragma unroll
  for (int a = 0; a < 8; ++a) {
    p[a] = __expf(dots[a] - mx);
    sum += p[a];
  }
  const float inv = 1.f / sum;
#pragma unroll
  for (int a = 0; a < 8; ++a) p[a] *= inv;
  u16* yp = y + (size_t)(b * 2048 + n) * 1024 + h * 128;
#pragma unroll 4
  for (int dd = 0; dd < 128; dd += 4) {
    float a0 = 0, a1 = 0, a2 = 0, a3 = 0;
#pragma unroll
    for (int a = 0; a < 8; ++a) {
      const float4 o4 = *(const float4*)&ovl[a][dd];
      a0 += p[a] * o4.x;
      a1 += p[a] * o4.y;
      a2 += p[a] * o4.z;
      a3 += p[a] * o4.w;
    }
    ushort4 o;
    o.x = f2bf(a0);
    o.y = f2bf(a1);
    o.z = f2bf(a2);
    o.w = f2bf(a3);
    *(ushort4*)(yp + dd) = o;
  }
}

extern "C" void kernel_launch(void* const* d_in, const int* in_sizes, int n_in,
                              void* d_out, int out_size, void* d_ws, size_t ws_size,
                              hipStream_t stream) {
  const float* inputs = (const float*)d_in[0];
  const float* ln_g = (const float*)d_in[1];
  const float* ln_b = (const float*)d_in[2];
  const float* q_anchor = (const float*)d_in[3];
  const float* W_qkv = (const float*)d_in[4];
  const float* b_qkv = (const float*)d_in[5];
  const float* W_an = (const float*)d_in[6];
  const float* b_an = (const float*)d_in[7];
  const float* W_n1 = (const float*)d_in[8];
  const float* b_n1 = (const float*)d_in[9];
  const float* W_n2 = (const float*)d_in[10];
  const float* b_n2 = (const float*)d_in[11];
  const float* W_n3 = (const float*)d_in[12];
  const float* b_n3 = (const float*)d_in[13];
  const float* W_k = (const float*)d_in[14];
  const float* b_k = (const float*)d_in[15];
  const float* W_o = (const float*)d_in[16];
  const float* b_o = (const float*)d_in[17];
  float* out = (float*)d_out;

  char* ws = (char*)d_ws;
  u16* qkv = (u16*)(ws);                                   // 16384*3072 bf16 = 96 MB
  u16* xbf = (u16*)(ws + 100663296);                       // 16384*1024 bf16 (x, later y)
  float* S = (float*)(ws + 100663296);                     // attn1 scores 4 MB (overlays dead x)
  u16* WqkvT = (u16*)(ws + 134217728);                     // 3072*1024 bf16
  u16* WoT = (u16*)(ws + 140509184);                       // 1024*1024 bf16
  float* att1 = (float*)(ws + 142606336);                  // 64*1024
  float* anp = (float*)(ws + 142868480);                   // 64*4096 (raw, pre-relu/perm)
  float* h1 = (float*)(ws + 143917056);                    // 64*1024
  float* h2 = (float*)(ws + 144179200);                    // 64*4096 (raw, pre-relu)
  float* onet = (float*)(ws + 145227776);                  // 64*1024
  float* kkb = (float*)(ws + 145489920);                   // 64*1024

  // 1) LayerNorm -> x bf16
  ln_kernel<<<16384, 256, 0, stream>>>(inputs, ln_g, ln_b, xbf);
  // 2) weight transposes (merged) + accumulation-buffer init (bias pre-fill)
  transpose2_bf16<<<dim3(32, 128), 256, 0, stream>>>(W_qkv, WqkvT, W_o, WoT);
  init_bufs<<<768, 256, 0, stream>>>(b_an, b_n1, b_n2, b_n3, b_k,
                                     att1, anp, h1, h2, onet, kkb);
  // 3) QKV GEMM -> qkv bf16
  gemm_bf16<0><<<dim3(64, 12), 512, 0, stream>>>(xbf, WqkvT, b_qkv, nullptr, qkv, nullptr,
                                                 16384, 3072, 1024);
  // 4) anchor attention: scores -> softmax -> PV (atomic-reduced into att1)
  attn1_scores<<<512, 256, 0, stream>>>(qkv, q_anchor, S);
  attn1_softmax<<<512, 256, 0, stream>>>(S);
  attn1_pv<<<512, 256, 0, stream>>>(qkv, S, att1);
  // 5) MLP chain: split-K MFMA GEMMs, atomic-accumulated into bias-preinit outputs;
  //    relu / an-permute applied on the consumer's A-load.
  mlp_mfma<0><<<dim3(64, 4), 256, 0, stream>>>(att1, W_an, anp, 1024, 4096, 256);
  mlp_mfma<2><<<dim3(16, 16), 256, 0, stream>>>(anp, W_n1, h1, 4096, 1024, 256);
  mlp_mfma<0><<<dim3(64, 4), 256, 0, stream>>>(h1, W_n2, h2, 1024, 4096, 256);
  mlp_mfma<1><<<dim3(16, 16), 256, 0, stream>>>(h2, W_n3, onet, 4096, 1024, 256);
  mlp_mfma<0><<<dim3(16, 8), 256, 0, stream>>>(onet, W_k, kkb, 1024, 1024, 128);
  // 6) query attention over 8 anchors -> y bf16 (reuses xbf buffer)
  attn2_kernel<<<512, 256, 0, stream>>>(qkv, kkb, onet, xbf);
  // 7) output GEMM + bias + residual -> d_out f32
  gemm_bf16<1><<<dim3(64, 4), 512, 0, stream>>>(xbf, WoT, b_o, inputs, nullptr, out,
                                                16384, 1024, 1024);
}

// Round 7
// 574.657 us; speedup vs baseline: 1.0464x; 1.0059x over previous
//
#include <hip/hip_runtime.h>
#include <cstdint>
#include <cstddef>

typedef unsigned short u16;
typedef __attribute__((ext_vector_type(8))) short short8;
typedef __attribute__((ext_vector_type(4))) float floatx4;
typedef __attribute__((ext_vector_type(16))) float floatx16;

__device__ __forceinline__ u16 f2bf(float f) {
  unsigned u = __float_as_uint(f);
  u += 0x7fffu + ((u >> 16) & 1u);
  return (u16)(u >> 16);
}
__device__ __forceinline__ float bf2f(u16 s) {
  return __uint_as_float(((unsigned)s) << 16);
}

// ---------------- prep: LayerNorm + both weight transposes + bias prefill ----------------
// grid 21184 blocks x 256 thr:
//   [0, 16384)        : ln rows
//   [16384, 20480)    : transpose tiles (x = t&31, y = t>>5; y<96 -> W_qkv else W_o)
//   [20480, 21184)    : bias prefill (float4 segments: anp|h1|h2|onet|kkb)
__global__ __launch_bounds__(256) void prep_kernel(const float* __restrict__ x,
                                                   const float* __restrict__ g,
                                                   const float* __restrict__ bta,
                                                   u16* __restrict__ xout,
                                                   const float* __restrict__ Wq,
                                                   u16* __restrict__ WqT,
                                                   const float* __restrict__ Wo,
                                                   u16* __restrict__ WoT,
                                                   const float* __restrict__ b_an,
                                                   const float* __restrict__ b_n1,
                                                   const float* __restrict__ b_n2,
                                                   const float* __restrict__ b_n3,
                                                   const float* __restrict__ b_k,
                                                   float* __restrict__ anp,
                                                   float* __restrict__ h1,
                                                   float* __restrict__ h2,
                                                   float* __restrict__ onet,
                                                   float* __restrict__ kkb) {
  __shared__ float t[32][33];
  __shared__ float red[4], red2[4];
  const int bid = blockIdx.x;
  const int tid = threadIdx.x;
  if (bid < 16384) {
    const int row = bid;
    const float4 v = ((const float4*)(x + (size_t)row * 1024))[tid];
    float s = v.x + v.y + v.z + v.w;
#pragma unroll
    for (int o = 32; o > 0; o >>= 1) s += __shfl_down(s, o);
    const int wv = tid >> 6, ln = tid & 63;
    if (ln == 0) red[wv] = s;
    __syncthreads();
    const float mean = (red[0] + red[1] + red[2] + red[3]) * (1.0f / 1024.0f);
    const float dx = v.x - mean, dy = v.y - mean, dz = v.z - mean, dw = v.w - mean;
    float s2 = dx * dx + dy * dy + dz * dz + dw * dw;
#pragma unroll
    for (int o = 32; o > 0; o >>= 1) s2 += __shfl_down(s2, o);
    if (ln == 0) red2[wv] = s2;
    __syncthreads();
    const float var = (red2[0] + red2[1] + red2[2] + red2[3]) * (1.0f / 1024.0f);
    const float rstd = rsqrtf(var + 1e-6f);
    const float4 gg = ((const float4*)g)[tid];
    const float4 bb = ((const float4*)bta)[tid];
    ushort4 o4;
    o4.x = f2bf(dx * rstd * gg.x + bb.x);
    o4.y = f2bf(dy * rstd * gg.y + bb.y);
    o4.z = f2bf(dz * rstd * gg.z + bb.z);
    o4.w = f2bf(dw * rstd * gg.w + bb.w);
    ((ushort4*)(xout + (size_t)row * 1024))[tid] = o4;
  } else if (bid < 20480) {
    const int t2 = bid - 16384;
    const int xb = t2 & 31, yb0 = t2 >> 5;
    const float* W;
    u16* WT;
    int N, yb;
    if (yb0 < 96) { W = Wq; WT = WqT; N = 3072; yb = yb0; }
    else { W = Wo; WT = WoT; N = 1024; yb = yb0 - 96; }
    const int kb = xb * 32, nb = yb * 32;
    const int tx = tid & 31, ty = tid >> 5;
#pragma unroll
    for (int i = ty; i < 32; i += 8) t[i][tx] = W[(size_t)(kb + i) * N + nb + tx];
    __syncthreads();
#pragma unroll
    for (int i = ty; i < 32; i += 8) WT[(size_t)(nb + i) * 1024 + kb + tx] = f2bf(t[tx][i]);
  } else {
    const int i = (bid - 20480) * 256 + tid;
    if (i < 65536) {
      ((float4*)anp)[i] = ((const float4*)b_an)[i & 1023];
    } else if (i < 81920) {
      const int j = i - 65536;
      ((float4*)h1)[j] = ((const float4*)b_n1)[j & 255];
    } else if (i < 147456) {
      const int j = i - 81920;
      ((float4*)h2)[j] = ((const float4*)b_n2)[j & 1023];
    } else if (i < 163840) {
      const int j = i - 147456;
      ((float4*)onet)[j] = ((const float4*)b_n3)[j & 255];
    } else {
      const int j = i - 163840;
      ((float4*)kkb)[j] = ((const float4*)b_k)[j & 255];
    }
  }
}

// ================= 256x256 pipelined bf16 MFMA GEMM (32x32x16) =================
// (unchanged from round 5/6)

__device__ __forceinline__ void stageG(const u16* __restrict__ gp, u16* lp, int K) {
  __builtin_amdgcn_global_load_lds((const __attribute__((address_space(1))) void*)gp,
                                   (__attribute__((address_space(3))) void*)lp, 16, 0, 0);
  __builtin_amdgcn_global_load_lds((const __attribute__((address_space(1))) void*)(gp + ((size_t)K << 6)),
                                   (__attribute__((address_space(3))) void*)(lp + 4096), 16, 0, 0);
}

__device__ __forceinline__ void rdA(short8 (&af)[2][4], const u16* sbuf, const int (&ab)[4],
                                    int halfoff) {
#pragma unroll
  for (int mi = 0; mi < 2; ++mi)
#pragma unroll
    for (int ks = 0; ks < 4; ++ks)
      af[mi][ks] = *(const short8*)(sbuf + halfoff + mi * 2048 + (ab[ks] ^ (mi << 5)));
}
__device__ __forceinline__ void rdB(short8 (&bf)[4], const u16* sbuf, const int (&bb)[4],
                                    int halfoff) {
#pragma unroll
  for (int ks = 0; ks < 4; ++ks)
    bf[ks] = *(const short8*)(sbuf + halfoff + bb[ks]);
}

template <int Q>
__device__ __forceinline__ void mfmaQ(floatx16 (&acc)[4][2], const short8 (&af)[2][4],
                                      const short8 (&bf)[4]) {
#pragma unroll
  for (int ks = 0; ks < 4; ++ks)
#pragma unroll
    for (int mi = 0; mi < 2; ++mi)
      acc[Q][mi] = __builtin_amdgcn_mfma_f32_32x32x16_bf16(af[mi][ks], bf[ks], acc[Q][mi], 0, 0, 0);
}

template <int B_>
__device__ __forceinline__ void gtile(int t, int NT, int K,
                                      u16 (&sA)[2][16384], u16 (&sB)[2][16384],
                                      const u16* gA_lo, const u16* gA_hi,
                                      const u16* gB_lo, const u16* gB_hi,
                                      u16* ldsA_cur, u16* ldsA_alt,
                                      u16* ldsB_cur, u16* ldsB_alt,
                                      const int (&ab)[4], const int (&bb)[4],
                                      floatx16 (&acc)[4][2],
                                      short8 (&afA)[2][4], short8 (&bfP)[4], short8 (&bfN)[4]) {
  rdA(afA, sA[B_], ab, 0);
  __builtin_amdgcn_sched_barrier(0);
  if (t + 1 < NT) stageG(gA_hi + ((t + 1) << 6), ldsA_alt + 8192, K);
  rdB(bfN, sB[B_], bb, 8192);  // B1(t)
  asm volatile("s_waitcnt lgkmcnt(4)" ::: "memory");
  __builtin_amdgcn_sched_barrier(0);
  __builtin_amdgcn_s_setprio(1);
  mfmaQ<0>(acc, afA, bfP);
  __builtin_amdgcn_s_setprio(0);
  if (t + 1 < NT) stageG(gB_lo + ((t + 1) << 6), ldsB_alt, K);
  asm volatile("s_waitcnt lgkmcnt(0)" ::: "memory");
  __builtin_amdgcn_sched_barrier(0);
  __builtin_amdgcn_s_setprio(1);
  mfmaQ<1>(acc, afA, bfN);
  __builtin_amdgcn_s_setprio(0);
  rdA(afA, sA[B_], ab, 8192);
  __builtin_amdgcn_s_barrier();
  if (t + 2 < NT) stageG(gA_lo + ((t + 2) << 6), ldsA_cur, K);
  asm volatile("s_waitcnt lgkmcnt(0)" ::: "memory");
  __builtin_amdgcn_sched_barrier(0);
  __builtin_amdgcn_s_setprio(1);
  mfmaQ<2>(acc, afA, bfN);
  __builtin_amdgcn_s_setprio(0);
  if (t + 2 < NT) stageG(gB_hi + ((t + 2) << 6), ldsB_cur + 8192, K);
  if (t + 2 < NT) {
    asm volatile("s_waitcnt vmcnt(4)" ::: "memory");
  } else {
    asm volatile("s_waitcnt vmcnt(0)" ::: "memory");
  }
  __builtin_amdgcn_s_barrier();
  if (t + 1 < NT) rdB(bfN, sB[B_ ^ 1], bb, 0);
  __builtin_amdgcn_sched_barrier(0);
  __builtin_amdgcn_s_setprio(1);
  mfmaQ<3>(acc, afA, bfP);
  __builtin_amdgcn_s_setprio(0);
}

template <int EPI>
__global__ __launch_bounds__(512, 2) void gemm_bf16(const u16* __restrict__ A,
                                                    const u16* __restrict__ BT,
                                                    const float* __restrict__ bias,
                                                    const float* __restrict__ extra,
                                                    u16* __restrict__ outB,
                                                    float* __restrict__ outF,
                                                    int M, int N, int K) {
  __shared__ u16 sA[2][16384];
  __shared__ u16 sB[2][16384];
  const int tid = threadIdx.x;
  const int wave = tid >> 6, lane = tid & 63;
  const int m0 = blockIdx.x * 256, n0 = blockIdx.y * 256;
  const int wr = wave >> 2, wc = wave & 3;
  const int l31 = lane & 31, l5 = lane >> 5, l7 = lane & 7;
  const int NT = K >> 6;

  const int fa = l7 ^ (l31 >> 3);
  const int fb = l7 ^ ((wc * 4 + (l31 >> 3)) & 7);
  int ab[4], bb[4];
#pragma unroll
  for (int ks = 0; ks < 4; ++ks) {
    const int kg = (ks << 1) + l5;
    ab[ks] = (wr * 64 + l31) * 64 + (((kg ^ fa) & 7) << 3);
    bb[ks] = (wc * 32 + l31) * 64 + (((kg ^ fb) & 7) << 3);
  }
  const int srow = wave * 8 + (lane >> 3);
  const int scol = ((lane & 7) ^ (lane >> 3) ^ wave) << 3;
  const u16* gA_lo = A + (size_t)(m0 + srow) * K + scol;
  const u16* gA_hi = A + (size_t)(m0 + 128 + srow) * K + scol;
  const u16* gB_lo = BT + (size_t)(n0 + srow) * K + scol;
  const u16* gB_hi = BT + (size_t)(n0 + 128 + srow) * K + scol;

  floatx16 acc[4][2];
#pragma unroll
  for (int q = 0; q < 4; ++q)
#pragma unroll
    for (int mi = 0; mi < 2; ++mi)
#pragma unroll
      for (int r = 0; r < 16; ++r) acc[q][mi][r] = 0.f;

  stageG(gA_lo, &sA[0][0] + wave * 512, K);
  stageG(gA_hi, &sA[0][8192] + wave * 512, K);
  stageG(gB_lo, &sB[0][0] + wave * 512, K);
  stageG(gB_hi, &sB[0][8192] + wave * 512, K);
  stageG(gA_lo + 64, &sA[1][0] + wave * 512, K);
  stageG(gB_hi + 64, &sB[1][8192] + wave * 512, K);
  asm volatile("s_waitcnt vmcnt(4)" ::: "memory");
  __builtin_amdgcn_s_barrier();

  short8 afA[2][4], bfX[4], bfY[4];
  rdB(bfX, sB[0], bb, 0);
  __builtin_amdgcn_sched_barrier(0);

  for (int t = 0; t < NT; t += 2) {
    gtile<0>(t, NT, K, sA, sB, gA_lo, gA_hi, gB_lo, gB_hi,
             &sA[0][0] + wave * 512, &sA[1][0] + wave * 512,
             &sB[0][0] + wave * 512, &sB[1][0] + wave * 512, ab, bb, acc, afA, bfX, bfY);
    gtile<1>(t + 1, NT, K, sA, sB, gA_lo, gA_hi, gB_lo, gB_hi,
             &sA[1][0] + wave * 512, &sA[0][0] + wave * 512,
             &sB[1][0] + wave * 512, &sB[0][0] + wave * 512, ab, bb, acc, afA, bfY, bfX);
  }

#pragma unroll
  for (int q = 0; q < 4; ++q) {
    const int QM = q >> 1, QN = QM ^ (q & 1);
    const int n = n0 + QN * 128 + wc * 32 + l31;
    const float bs = bias[n];
#pragma unroll
    for (int mi = 0; mi < 2; ++mi) {
      const int mb = m0 + QM * 128 + wr * 64 + mi * 32 + 4 * l5;
#pragma unroll
      for (int reg = 0; reg < 16; ++reg) {
        const int m = mb + (reg & 3) + 8 * (reg >> 2);
        const float v = acc[q][mi][reg] + bs;
        if (EPI == 0)
          outB[(size_t)m * N + n] = f2bf(v);
        else
          outF[(size_t)m * N + n] = v + extra[(size_t)m * N + n];
      }
    }
  }
}

// ---------------- fused anchor attention: scores + softmax + PV in one kernel ----------------
// grid 256 = bh(64) x anchor-pair(4); 512 threads; S kept in LDS; att1 written directly.
__global__ __launch_bounds__(512) void attn1_fused(const u16* __restrict__ qkv,
                                                   const float* __restrict__ q_anchor,
                                                   float* __restrict__ att1) {
  __shared__ u16 kv[256 * 132];     // K/V tile, rows padded to 132 u16
  __shared__ float S2[2][2048];     // scores / P (unnormalized) ; reused as reduce scratch
  __shared__ float qa2[2][128];
  __shared__ float red[16];         // [a*4+wv] max, [8 + a*4+wv] sum
  const int tid = threadIdx.x;
  const int bh = blockIdx.x >> 2, ag = blockIdx.x & 3;
  const int b = bh >> 3, h = bh & 7;
  const int a0 = ag * 2;

  for (int i = tid; i < 256; i += 512)
    qa2[i >> 7][i & 127] = q_anchor[h * 1024 + (a0 + (i >> 7)) * 128 + (i & 127)];

  const float scale = 0.0883883476483184f;
  const size_t rowbase = (size_t)b * 2048;

  // ---- Phase 1: scores for 2 anchors x 2048 keys
  {
    const int a = tid >> 8, nn = tid & 255;
    for (int T = 0; T < 8; ++T) {
      __syncthreads();
      // stage K tile (256 rows x 128 u16), ushort4 chunks
#pragma unroll
      for (int p = 0; p < 16; ++p) {
        const int c = p * 512 + tid;
        const int r = c >> 5, off = (c & 31) * 4;
        const ushort4 kk = *(const ushort4*)(qkv + (rowbase + T * 256 + r) * 3072 + 1024 + h * 128 + off);
        *(ushort4*)&kv[r * 132 + off] = kk;
      }
      __syncthreads();
      float dot = 0.f;
#pragma unroll 8
      for (int dd = 0; dd < 128; dd += 4) {
        const ushort4 k4 = *(const ushort4*)&kv[nn * 132 + dd];
        const float4 q4 = *(const float4*)&qa2[a][dd];
        dot += q4.x * bf2f(k4.x) + q4.y * bf2f(k4.y) + q4.z * bf2f(k4.z) + q4.w * bf2f(k4.w);
      }
      S2[a][T * 256 + nn] = dot * scale;
    }
  }
  __syncthreads();
  // ---- softmax (per anchor row of 2048); leave P unnormalized, remember sum
  {
    const int a = tid >> 8, li = tid & 255;
    const int wv = (tid >> 6) & 3, ln = tid & 63;
    float mx = -1e30f;
#pragma unroll
    for (int k = 0; k < 8; ++k) mx = fmaxf(mx, S2[a][li + k * 256]);
#pragma unroll
    for (int o = 32; o > 0; o >>= 1) mx = fmaxf(mx, __shfl_xor(mx, o));
    if (ln == 0) red[a * 4 + wv] = mx;
    __syncthreads();
    mx = fmaxf(fmaxf(red[a * 4], red[a * 4 + 1]), fmaxf(red[a * 4 + 2], red[a * 4 + 3]));
    float sum = 0.f;
#pragma unroll
    for (int k = 0; k < 8; ++k) {
      const float e = __expf(S2[a][li + k * 256] - mx);
      S2[a][li + k * 256] = e;
      sum += e;
    }
#pragma unroll
    for (int o = 32; o > 0; o >>= 1) sum += __shfl_xor(sum, o);
    if (ln == 0) red[8 + a * 4 + wv] = sum;
  }
  __syncthreads();
  // ---- Phase 2: PV. thread = (a2 = tid&1, dq = (tid>>1)&31, s = tid>>6)
  {
    const int a2 = tid & 1, dq = (tid >> 1) & 31, s = tid >> 6;
    float acc0 = 0.f, acc1 = 0.f, acc2 = 0.f, acc3 = 0.f;
    for (int T = 0; T < 8; ++T) {
      __syncthreads();
#pragma unroll
      for (int p = 0; p < 16; ++p) {
        const int c = p * 512 + tid;
        const int r = c >> 5, off = (c & 31) * 4;
        const ushort4 vv = *(const ushort4*)(qkv + (rowbase + T * 256 + r) * 3072 + 2048 + h * 128 + off);
        *(ushort4*)&kv[r * 132 + off] = vv;
      }
      __syncthreads();
#pragma unroll 4
      for (int j = 0; j < 32; ++j) {
        const int nl = s * 32 + j;
        const float pw = S2[a2][T * 256 + nl];
        const ushort4 v4 = *(const ushort4*)&kv[nl * 132 + dq * 4];
        acc0 += pw * bf2f(v4.x);
        acc1 += pw * bf2f(v4.y);
        acc2 += pw * bf2f(v4.z);
        acc3 += pw * bf2f(v4.w);
      }
    }
    __syncthreads();  // all P reads done -> S2 reusable as scratch
    float* scratch = &S2[0][0];  // 2048 floats: [((a2*32+dq)*4+k)*8 + s]
    scratch[((a2 * 32 + dq) * 4 + 0) * 8 + s] = acc0;
    scratch[((a2 * 32 + dq) * 4 + 1) * 8 + s] = acc1;
    scratch[((a2 * 32 + dq) * 4 + 2) * 8 + s] = acc2;
    scratch[((a2 * 32 + dq) * 4 + 3) * 8 + s] = acc3;
  }
  __syncthreads();
  if (tid < 256) {
    const int a2 = tid >> 7, dq = (tid >> 2) & 31, k = tid & 3;
    const float* scratch = &S2[0][0];
    const float* sp = &scratch[((a2 * 32 + dq) * 4 + k) * 8];
    float tot = sp[0] + sp[1] + sp[2] + sp[3] + sp[4] + sp[5] + sp[6] + sp[7];
    const float inv = 1.f / (red[8 + a2 * 4] + red[8 + a2 * 4 + 1] +
                             red[8 + a2 * 4 + 2] + red[8 + a2 * 4 + 3]);
    att1[(size_t)bh * 1024 + (a0 + a2) * 128 + dq * 4 + k] = tot * inv;
  }
}

// ---------------- MLP MFMA GEMM with fused epilogue (unchanged from round 6) ----------------
template <int AMODE>
__global__ __launch_bounds__(256) void mlp_mfma(const float* __restrict__ A,
                                                const float* __restrict__ W,
                                                float* __restrict__ outp,
                                                int K, int N, int KC) {
  __shared__ float sW[64][33];
  const int tid = threadIdx.x;
  const int lane = tid & 63, wave = tid >> 6;
  const int wm = wave * 16;
  const int n0 = blockIdx.x * 64;
  const int kbeg = blockIdx.y * KC;
  const int l15 = lane & 15, kq8 = (lane >> 4) * 8;
  const int arow = wm + l15;

  floatx4 acc[4];
  const floatx4 zero = {0.f, 0.f, 0.f, 0.f};
#pragma unroll
  for (int j = 0; j < 4; ++j) acc[j] = zero;

  for (int kc = 0; kc < KC; kc += 32) {
    const int kbase = kbeg + kc;
    __syncthreads();
#pragma unroll
    for (int p = 0; p < 8; ++p) {
      const int k = p * 4 + wave;
      sW[lane][k] = W[(size_t)(kbase + k) * N + n0 + lane];
    }
    const float* ap;
    if (AMODE == 2) {
      const int k = kbase + kq8;
      ap = A + (size_t)(arow >> 3) * 32768 + (size_t)(k >> 9) * 4096 + (arow & 7) * 512 + (k & 511);
    } else {
      ap = A + (size_t)arow * K + kbase + kq8;
    }
    float4 a0 = *(const float4*)ap;
    float4 a1 = *(const float4*)(ap + 4);
    if (AMODE >= 1) {
      a0.x = fmaxf(a0.x, 0.f); a0.y = fmaxf(a0.y, 0.f);
      a0.z = fmaxf(a0.z, 0.f); a0.w = fmaxf(a0.w, 0.f);
      a1.x = fmaxf(a1.x, 0.f); a1.y = fmaxf(a1.y, 0.f);
      a1.z = fmaxf(a1.z, 0.f); a1.w = fmaxf(a1.w, 0.f);
    }
    short8 af;
    af[0] = (short)f2bf(a0.x); af[1] = (short)f2bf(a0.y);
    af[2] = (short)f2bf(a0.z); af[3] = (short)f2bf(a0.w);
    af[4] = (short)f2bf(a1.x); af[5] = (short)f2bf(a1.y);
    af[6] = (short)f2bf(a1.z); af[7] = (short)f2bf(a1.w);
    __syncthreads();
#pragma unroll
    for (int j = 0; j < 4; ++j) {
      const float* wp = &sW[j * 16 + l15][kq8];
      short8 bf;
      bf[0] = (short)f2bf(wp[0]); bf[1] = (short)f2bf(wp[1]);
      bf[2] = (short)f2bf(wp[2]); bf[3] = (short)f2bf(wp[3]);
      bf[4] = (short)f2bf(wp[4]); bf[5] = (short)f2bf(wp[5]);
      bf[6] = (short)f2bf(wp[6]); bf[7] = (short)f2bf(wp[7]);
      acc[j] = __builtin_amdgcn_mfma_f32_16x16x32_bf16(af, bf, acc[j], 0, 0, 0);
    }
  }
  const int q = lane >> 4;
#pragma unroll
  for (int j = 0; j < 4; ++j)
#pragma unroll
    for (int r = 0; r < 4; ++r) {
      const int m = wm + q * 4 + r;
      const int n = n0 + j * 16 + l15;
      atomicAdd(&outp[(size_t)m * N + n], acc[j][r]);
    }
}

// ---------------- attention 2: 2048 queries vs 8 anchor keys + PV ----------------
__global__ __launch_bounds__(256) void attn2_kernel(const u16* __restrict__ qkv,
                                                    const float* __restrict__ kk,
                                                    const float* __restrict__ onet,
                                                    u16* __restrict__ y) {
  __shared__ float kkl[8][128];
  __shared__ float ovl[8][128];
  const int tid = threadIdx.x;
  const int chunk = blockIdx.x & 7, bh = blockIdx.x >> 3;
  const int b = bh >> 3, h = bh & 7;
  for (int i = tid; i < 1024; i += 256) {
    const int a = i >> 7, d = i & 127;
    kkl[a][d] = kk[(size_t)(b * 8 + a) * 1024 + h * 128 + d];
    ovl[a][d] = onet[(size_t)(b * 8 + a) * 1024 + h * 128 + d];
  }
  __syncthreads();
  const int n = chunk * 256 + tid;
  const u16* qp = qkv + (size_t)(b * 2048 + n) * 3072 + h * 128;
  float dots[8] = {0, 0, 0, 0, 0, 0, 0, 0};
#pragma unroll 4
  for (int dd = 0; dd < 128; dd += 4) {
    const ushort4 q4 = *(const ushort4*)(qp + dd);
    const float q0 = bf2f(q4.x), q1 = bf2f(q4.y), q2 = bf2f(q4.z), q3 = bf2f(q4.w);
#pragma unroll
    for (int a = 0; a < 8; ++a) {
      const float4 k4 = *(const float4*)&kkl[a][dd];
      dots[a] += k4.x * q0 + k4.y * q1 + k4.z * q2 + k4.w * q3;
    }
  }
  const float scale = 0.0883883476483184f;
  float mx = -1e30f;
#pragma unroll
  for (int a = 0; a < 8; ++a) {
    dots[a] *= scale;
    mx = fmaxf(mx, dots[a]);
  }
  float p[8];
  float sum = 0.f;
#pragma unroll
  for (int a = 0; a < 8; ++a) {
    p[a] = __expf(dots[a] - mx);
    sum += p[a];
  }
  const float inv = 1.f / sum;
#pragma unroll
  for (int a = 0; a < 8; ++a) p[a] *= inv;
  u16* yp = y + (size_t)(b * 2048 + n) * 1024 + h * 128;
#pragma unroll 4
  for (int dd = 0; dd < 128; dd += 4) {
    float a0 = 0, a1 = 0, a2 = 0, a3 = 0;
#pragma unroll
    for (int a = 0; a < 8; ++a) {
      const float4 o4 = *(const float4*)&ovl[a][dd];
      a0 += p[a] * o4.x;
      a1 += p[a] * o4.y;
      a2 += p[a] * o4.z;
      a3 += p[a] * o4.w;
    }
    ushort4 o;
    o.x = f2bf(a0);
    o.y = f2bf(a1);
    o.z = f2bf(a2);
    o.w = f2bf(a3);
    *(ushort4*)(yp + dd) = o;
  }
}

extern "C" void kernel_launch(void* const* d_in, const int* in_sizes, int n_in,
                              void* d_out, int out_size, void* d_ws, size_t ws_size,
                              hipStream_t stream) {
  const float* inputs = (const float*)d_in[0];
  const float* ln_g = (const float*)d_in[1];
  const float* ln_b = (const float*)d_in[2];
  const float* q_anchor = (const float*)d_in[3];
  const float* W_qkv = (const float*)d_in[4];
  const float* b_qkv = (const float*)d_in[5];
  const float* W_an = (const float*)d_in[6];
  const float* b_an = (const float*)d_in[7];
  const float* W_n1 = (const float*)d_in[8];
  const float* b_n1 = (const float*)d_in[9];
  const float* W_n2 = (const float*)d_in[10];
  const float* b_n2 = (const float*)d_in[11];
  const float* W_n3 = (const float*)d_in[12];
  const float* b_n3 = (const float*)d_in[13];
  const float* W_k = (const float*)d_in[14];
  const float* b_k = (const float*)d_in[15];
  const float* W_o = (const float*)d_in[16];
  const float* b_o = (const float*)d_in[17];
  float* out = (float*)d_out;

  char* ws = (char*)d_ws;
  u16* qkv = (u16*)(ws);                                   // 16384*3072 bf16 = 96 MB
  u16* xbf = (u16*)(ws + 100663296);                       // 16384*1024 bf16 (x, later y)
  u16* WqkvT = (u16*)(ws + 134217728);                     // 3072*1024 bf16
  u16* WoT = (u16*)(ws + 140509184);                       // 1024*1024 bf16
  float* att1 = (float*)(ws + 142606336);                  // 64*1024
  float* anp = (float*)(ws + 142868480);                   // 64*4096 (raw, pre-relu/perm)
  float* h1 = (float*)(ws + 143917056);                    // 64*1024
  float* h2 = (float*)(ws + 144179200);                    // 64*4096 (raw, pre-relu)
  float* onet = (float*)(ws + 145227776);                  // 64*1024
  float* kkb = (float*)(ws + 145489920);                   // 64*1024

  // 1) prep: LayerNorm + weight transposes + bias prefill (one launch)
  prep_kernel<<<21184, 256, 0, stream>>>(inputs, ln_g, ln_b, xbf,
                                         W_qkv, WqkvT, W_o, WoT,
                                         b_an, b_n1, b_n2, b_n3, b_k,
                                         anp, h1, h2, onet, kkb);
  // 2) QKV GEMM -> qkv bf16
  gemm_bf16<0><<<dim3(64, 12), 512, 0, stream>>>(xbf, WqkvT, b_qkv, nullptr, qkv, nullptr,
                                                 16384, 3072, 1024);
  // 3) fused anchor attention -> att1 (no S buffer, no atomics)
  attn1_fused<<<256, 512, 0, stream>>>(qkv, q_anchor, att1);
  // 4) MLP chain: split-K MFMA GEMMs, atomic-accumulated into bias-preinit outputs
  mlp_mfma<0><<<dim3(64, 4), 256, 0, stream>>>(att1, W_an, anp, 1024, 4096, 256);
  mlp_mfma<2><<<dim3(16, 16), 256, 0, stream>>>(anp, W_n1, h1, 4096, 1024, 256);
  mlp_mfma<0><<<dim3(64, 4), 256, 0, stream>>>(h1, W_n2, h2, 1024, 4096, 256);
  mlp_mfma<1><<<dim3(16, 16), 256, 0, stream>>>(h2, W_n3, onet, 4096, 1024, 256);
  mlp_mfma<0><<<dim3(16, 8), 256, 0, stream>>>(onet, W_k, kkb, 1024, 1024, 128);
  // 5) query attention over 8 anchors -> y bf16 (reuses xbf buffer)
  attn2_kernel<<<512, 256, 0, stream>>>(qkv, kkb, onet, xbf);
  // 6) output GEMM + bias + residual -> d_out f32
  gemm_bf16<1><<<dim3(64, 4), 512, 0, stream>>>(xbf, WoT, b_o, inputs, nullptr, out,
                                                16384, 1024, 1024);
}

// Round 8
// 519.860 us; speedup vs baseline: 1.1567x; 1.1054x over previous
//
#include <hip/hip_runtime.h>
#include <cstdint>
#include <cstddef>

typedef unsigned short u16;
typedef __attribute__((ext_vector_type(8))) short short8;
typedef __attribute__((ext_vector_type(4))) float floatx4;
typedef __attribute__((ext_vector_type(16))) float floatx16;

__device__ __forceinline__ u16 f2bf(float f) {
  unsigned u = __float_as_uint(f);
  u += 0x7fffu + ((u >> 16) & 1u);
  return (u16)(u >> 16);
}
__device__ __forceinline__ float bf2f(u16 s) {
  return __uint_as_float(((unsigned)s) << 16);
}

// ---------------- prep: LayerNorm + both weight transposes + bias prefill ----------------
__global__ __launch_bounds__(256) void prep_kernel(const float* __restrict__ x,
                                                   const float* __restrict__ g,
                                                   const float* __restrict__ bta,
                                                   u16* __restrict__ xout,
                                                   const float* __restrict__ Wq,
                                                   u16* __restrict__ WqT,
                                                   const float* __restrict__ Wo,
                                                   u16* __restrict__ WoT,
                                                   const float* __restrict__ b_an,
                                                   const float* __restrict__ b_n1,
                                                   const float* __restrict__ b_n2,
                                                   const float* __restrict__ b_n3,
                                                   const float* __restrict__ b_k,
                                                   float* __restrict__ anp,
                                                   float* __restrict__ h1,
                                                   float* __restrict__ h2,
                                                   float* __restrict__ onet,
                                                   float* __restrict__ kkb) {
  __shared__ float t[32][33];
  __shared__ float red[4], red2[4];
  const int bid = blockIdx.x;
  const int tid = threadIdx.x;
  if (bid < 16384) {
    const int row = bid;
    const float4 v = ((const float4*)(x + (size_t)row * 1024))[tid];
    float s = v.x + v.y + v.z + v.w;
#pragma unroll
    for (int o = 32; o > 0; o >>= 1) s += __shfl_down(s, o);
    const int wv = tid >> 6, ln = tid & 63;
    if (ln == 0) red[wv] = s;
    __syncthreads();
    const float mean = (red[0] + red[1] + red[2] + red[3]) * (1.0f / 1024.0f);
    const float dx = v.x - mean, dy = v.y - mean, dz = v.z - mean, dw = v.w - mean;
    float s2 = dx * dx + dy * dy + dz * dz + dw * dw;
#pragma unroll
    for (int o = 32; o > 0; o >>= 1) s2 += __shfl_down(s2, o);
    if (ln == 0) red2[wv] = s2;
    __syncthreads();
    const float var = (red2[0] + red2[1] + red2[2] + red2[3]) * (1.0f / 1024.0f);
    const float rstd = rsqrtf(var + 1e-6f);
    const float4 gg = ((const float4*)g)[tid];
    const float4 bb = ((const float4*)bta)[tid];
    ushort4 o4;
    o4.x = f2bf(dx * rstd * gg.x + bb.x);
    o4.y = f2bf(dy * rstd * gg.y + bb.y);
    o4.z = f2bf(dz * rstd * gg.z + bb.z);
    o4.w = f2bf(dw * rstd * gg.w + bb.w);
    ((ushort4*)(xout + (size_t)row * 1024))[tid] = o4;
  } else if (bid < 20480) {
    const int t2 = bid - 16384;
    const int xb = t2 & 31, yb0 = t2 >> 5;
    const float* W;
    u16* WT;
    int N, yb;
    if (yb0 < 96) { W = Wq; WT = WqT; N = 3072; yb = yb0; }
    else { W = Wo; WT = WoT; N = 1024; yb = yb0 - 96; }
    const int kb = xb * 32, nb = yb * 32;
    const int tx = tid & 31, ty = tid >> 5;
#pragma unroll
    for (int i = ty; i < 32; i += 8) t[i][tx] = W[(size_t)(kb + i) * N + nb + tx];
    __syncthreads();
#pragma unroll
    for (int i = ty; i < 32; i += 8) WT[(size_t)(nb + i) * 1024 + kb + tx] = f2bf(t[tx][i]);
  } else {
    const int i = (bid - 20480) * 256 + tid;
    if (i < 65536) {
      ((float4*)anp)[i] = ((const float4*)b_an)[i & 1023];
    } else if (i < 81920) {
      const int j = i - 65536;
      ((float4*)h1)[j] = ((const float4*)b_n1)[j & 255];
    } else if (i < 147456) {
      const int j = i - 81920;
      ((float4*)h2)[j] = ((const float4*)b_n2)[j & 1023];
    } else if (i < 163840) {
      const int j = i - 147456;
      ((float4*)onet)[j] = ((const float4*)b_n3)[j & 255];
    } else {
      const int j = i - 163840;
      ((float4*)kkb)[j] = ((const float4*)b_k)[j & 255];
    }
  }
}

// ================= 256x256 pipelined bf16 MFMA GEMM (32x32x16) =================
// (unchanged from round 5/6/7)

__device__ __forceinline__ void stageG(const u16* __restrict__ gp, u16* lp, int K) {
  __builtin_amdgcn_global_load_lds((const __attribute__((address_space(1))) void*)gp,
                                   (__attribute__((address_space(3))) void*)lp, 16, 0, 0);
  __builtin_amdgcn_global_load_lds((const __attribute__((address_space(1))) void*)(gp + ((size_t)K << 6)),
                                   (__attribute__((address_space(3))) void*)(lp + 4096), 16, 0, 0);
}

__device__ __forceinline__ void rdA(short8 (&af)[2][4], const u16* sbuf, const int (&ab)[4],
                                    int halfoff) {
#pragma unroll
  for (int mi = 0; mi < 2; ++mi)
#pragma unroll
    for (int ks = 0; ks < 4; ++ks)
      af[mi][ks] = *(const short8*)(sbuf + halfoff + mi * 2048 + (ab[ks] ^ (mi << 5)));
}
__device__ __forceinline__ void rdB(short8 (&bf)[4], const u16* sbuf, const int (&bb)[4],
                                    int halfoff) {
#pragma unroll
  for (int ks = 0; ks < 4; ++ks)
    bf[ks] = *(const short8*)(sbuf + halfoff + bb[ks]);
}

template <int Q>
__device__ __forceinline__ void mfmaQ(floatx16 (&acc)[4][2], const short8 (&af)[2][4],
                                      const short8 (&bf)[4]) {
#pragma unroll
  for (int ks = 0; ks < 4; ++ks)
#pragma unroll
    for (int mi = 0; mi < 2; ++mi)
      acc[Q][mi] = __builtin_amdgcn_mfma_f32_32x32x16_bf16(af[mi][ks], bf[ks], acc[Q][mi], 0, 0, 0);
}

template <int B_>
__device__ __forceinline__ void gtile(int t, int NT, int K,
                                      u16 (&sA)[2][16384], u16 (&sB)[2][16384],
                                      const u16* gA_lo, const u16* gA_hi,
                                      const u16* gB_lo, const u16* gB_hi,
                                      u16* ldsA_cur, u16* ldsA_alt,
                                      u16* ldsB_cur, u16* ldsB_alt,
                                      const int (&ab)[4], const int (&bb)[4],
                                      floatx16 (&acc)[4][2],
                                      short8 (&afA)[2][4], short8 (&bfP)[4], short8 (&bfN)[4]) {
  rdA(afA, sA[B_], ab, 0);
  __builtin_amdgcn_sched_barrier(0);
  if (t + 1 < NT) stageG(gA_hi + ((t + 1) << 6), ldsA_alt + 8192, K);
  rdB(bfN, sB[B_], bb, 8192);  // B1(t)
  asm volatile("s_waitcnt lgkmcnt(4)" ::: "memory");
  __builtin_amdgcn_sched_barrier(0);
  __builtin_amdgcn_s_setprio(1);
  mfmaQ<0>(acc, afA, bfP);
  __builtin_amdgcn_s_setprio(0);
  if (t + 1 < NT) stageG(gB_lo + ((t + 1) << 6), ldsB_alt, K);
  asm volatile("s_waitcnt lgkmcnt(0)" ::: "memory");
  __builtin_amdgcn_sched_barrier(0);
  __builtin_amdgcn_s_setprio(1);
  mfmaQ<1>(acc, afA, bfN);
  __builtin_amdgcn_s_setprio(0);
  rdA(afA, sA[B_], ab, 8192);
  __builtin_amdgcn_s_barrier();
  if (t + 2 < NT) stageG(gA_lo + ((t + 2) << 6), ldsA_cur, K);
  asm volatile("s_waitcnt lgkmcnt(0)" ::: "memory");
  __builtin_amdgcn_sched_barrier(0);
  __builtin_amdgcn_s_setprio(1);
  mfmaQ<2>(acc, afA, bfN);
  __builtin_amdgcn_s_setprio(0);
  if (t + 2 < NT) stageG(gB_hi + ((t + 2) << 6), ldsB_cur + 8192, K);
  if (t + 2 < NT) {
    asm volatile("s_waitcnt vmcnt(4)" ::: "memory");
  } else {
    asm volatile("s_waitcnt vmcnt(0)" ::: "memory");
  }
  __builtin_amdgcn_s_barrier();
  if (t + 1 < NT) rdB(bfN, sB[B_ ^ 1], bb, 0);
  __builtin_amdgcn_sched_barrier(0);
  __builtin_amdgcn_s_setprio(1);
  mfmaQ<3>(acc, afA, bfP);
  __builtin_amdgcn_s_setprio(0);
}

template <int EPI>
__global__ __launch_bounds__(512, 2) void gemm_bf16(const u16* __restrict__ A,
                                                    const u16* __restrict__ BT,
                                                    const float* __restrict__ bias,
                                                    const float* __restrict__ extra,
                                                    u16* __restrict__ outB,
                                                    float* __restrict__ outF,
                                                    int M, int N, int K) {
  __shared__ u16 sA[2][16384];
  __shared__ u16 sB[2][16384];
  const int tid = threadIdx.x;
  const int wave = tid >> 6, lane = tid & 63;
  const int m0 = blockIdx.x * 256, n0 = blockIdx.y * 256;
  const int wr = wave >> 2, wc = wave & 3;
  const int l31 = lane & 31, l5 = lane >> 5, l7 = lane & 7;
  const int NT = K >> 6;

  const int fa = l7 ^ (l31 >> 3);
  const int fb = l7 ^ ((wc * 4 + (l31 >> 3)) & 7);
  int ab[4], bb[4];
#pragma unroll
  for (int ks = 0; ks < 4; ++ks) {
    const int kg = (ks << 1) + l5;
    ab[ks] = (wr * 64 + l31) * 64 + (((kg ^ fa) & 7) << 3);
    bb[ks] = (wc * 32 + l31) * 64 + (((kg ^ fb) & 7) << 3);
  }
  const int srow = wave * 8 + (lane >> 3);
  const int scol = ((lane & 7) ^ (lane >> 3) ^ wave) << 3;
  const u16* gA_lo = A + (size_t)(m0 + srow) * K + scol;
  const u16* gA_hi = A + (size_t)(m0 + 128 + srow) * K + scol;
  const u16* gB_lo = BT + (size_t)(n0 + srow) * K + scol;
  const u16* gB_hi = BT + (size_t)(n0 + 128 + srow) * K + scol;

  floatx16 acc[4][2];
#pragma unroll
  for (int q = 0; q < 4; ++q)
#pragma unroll
    for (int mi = 0; mi < 2; ++mi)
#pragma unroll
      for (int r = 0; r < 16; ++r) acc[q][mi][r] = 0.f;

  stageG(gA_lo, &sA[0][0] + wave * 512, K);
  stageG(gA_hi, &sA[0][8192] + wave * 512, K);
  stageG(gB_lo, &sB[0][0] + wave * 512, K);
  stageG(gB_hi, &sB[0][8192] + wave * 512, K);
  stageG(gA_lo + 64, &sA[1][0] + wave * 512, K);
  stageG(gB_hi + 64, &sB[1][8192] + wave * 512, K);
  asm volatile("s_waitcnt vmcnt(4)" ::: "memory");
  __builtin_amdgcn_s_barrier();

  short8 afA[2][4], bfX[4], bfY[4];
  rdB(bfX, sB[0], bb, 0);
  __builtin_amdgcn_sched_barrier(0);

  for (int t = 0; t < NT; t += 2) {
    gtile<0>(t, NT, K, sA, sB, gA_lo, gA_hi, gB_lo, gB_hi,
             &sA[0][0] + wave * 512, &sA[1][0] + wave * 512,
             &sB[0][0] + wave * 512, &sB[1][0] + wave * 512, ab, bb, acc, afA, bfX, bfY);
    gtile<1>(t + 1, NT, K, sA, sB, gA_lo, gA_hi, gB_lo, gB_hi,
             &sA[1][0] + wave * 512, &sA[0][0] + wave * 512,
             &sB[1][0] + wave * 512, &sB[0][0] + wave * 512, ab, bb, acc, afA, bfY, bfX);
  }

#pragma unroll
  for (int q = 0; q < 4; ++q) {
    const int QM = q >> 1, QN = QM ^ (q & 1);
    const int n = n0 + QN * 128 + wc * 32 + l31;
    const float bs = bias[n];
#pragma unroll
    for (int mi = 0; mi < 2; ++mi) {
      const int mb = m0 + QM * 128 + wr * 64 + mi * 32 + 4 * l5;
#pragma unroll
      for (int reg = 0; reg < 16; ++reg) {
        const int m = mb + (reg & 3) + 8 * (reg >> 2);
        const float v = acc[q][mi][reg] + bs;
        if (EPI == 0)
          outB[(size_t)m * N + n] = f2bf(v);
        else
          outF[(size_t)m * N + n] = v + extra[(size_t)m * N + n];
      }
    }
  }
}

// ---------------- fused anchor attention (unchanged from round 7) ----------------
__global__ __launch_bounds__(512) void attn1_fused(const u16* __restrict__ qkv,
                                                   const float* __restrict__ q_anchor,
                                                   float* __restrict__ att1) {
  __shared__ u16 kv[256 * 132];
  __shared__ float S2[2][2048];
  __shared__ float qa2[2][128];
  __shared__ float red[16];
  const int tid = threadIdx.x;
  const int bh = blockIdx.x >> 2, ag = blockIdx.x & 3;
  const int b = bh >> 3, h = bh & 7;
  const int a0 = ag * 2;

  for (int i = tid; i < 256; i += 512)
    qa2[i >> 7][i & 127] = q_anchor[h * 1024 + (a0 + (i >> 7)) * 128 + (i & 127)];

  const float scale = 0.0883883476483184f;
  const size_t rowbase = (size_t)b * 2048;

  {
    const int a = tid >> 8, nn = tid & 255;
    for (int T = 0; T < 8; ++T) {
      __syncthreads();
#pragma unroll
      for (int p = 0; p < 16; ++p) {
        const int c = p * 512 + tid;
        const int r = c >> 5, off = (c & 31) * 4;
        const ushort4 kk = *(const ushort4*)(qkv + (rowbase + T * 256 + r) * 3072 + 1024 + h * 128 + off);
        *(ushort4*)&kv[r * 132 + off] = kk;
      }
      __syncthreads();
      float dot = 0.f;
#pragma unroll 8
      for (int dd = 0; dd < 128; dd += 4) {
        const ushort4 k4 = *(const ushort4*)&kv[nn * 132 + dd];
        const float4 q4 = *(const float4*)&qa2[a][dd];
        dot += q4.x * bf2f(k4.x) + q4.y * bf2f(k4.y) + q4.z * bf2f(k4.z) + q4.w * bf2f(k4.w);
      }
      S2[a][T * 256 + nn] = dot * scale;
    }
  }
  __syncthreads();
  {
    const int a = tid >> 8, li = tid & 255;
    const int wv = (tid >> 6) & 3, ln = tid & 63;
    float mx = -1e30f;
#pragma unroll
    for (int k = 0; k < 8; ++k) mx = fmaxf(mx, S2[a][li + k * 256]);
#pragma unroll
    for (int o = 32; o > 0; o >>= 1) mx = fmaxf(mx, __shfl_xor(mx, o));
    if (ln == 0) red[a * 4 + wv] = mx;
    __syncthreads();
    mx = fmaxf(fmaxf(red[a * 4], red[a * 4 + 1]), fmaxf(red[a * 4 + 2], red[a * 4 + 3]));
    float sum = 0.f;
#pragma unroll
    for (int k = 0; k < 8; ++k) {
      const float e = __expf(S2[a][li + k * 256] - mx);
      S2[a][li + k * 256] = e;
      sum += e;
    }
#pragma unroll
    for (int o = 32; o > 0; o >>= 1) sum += __shfl_xor(sum, o);
    if (ln == 0) red[8 + a * 4 + wv] = sum;
  }
  __syncthreads();
  {
    const int a2 = tid & 1, dq = (tid >> 1) & 31, s = tid >> 6;
    float acc0 = 0.f, acc1 = 0.f, acc2 = 0.f, acc3 = 0.f;
    for (int T = 0; T < 8; ++T) {
      __syncthreads();
#pragma unroll
      for (int p = 0; p < 16; ++p) {
        const int c = p * 512 + tid;
        const int r = c >> 5, off = (c & 31) * 4;
        const ushort4 vv = *(const ushort4*)(qkv + (rowbase + T * 256 + r) * 3072 + 2048 + h * 128 + off);
        *(ushort4*)&kv[r * 132 + off] = vv;
      }
      __syncthreads();
#pragma unroll 4
      for (int j = 0; j < 32; ++j) {
        const int nl = s * 32 + j;
        const float pw = S2[a2][T * 256 + nl];
        const ushort4 v4 = *(const ushort4*)&kv[nl * 132 + dq * 4];
        acc0 += pw * bf2f(v4.x);
        acc1 += pw * bf2f(v4.y);
        acc2 += pw * bf2f(v4.z);
        acc3 += pw * bf2f(v4.w);
      }
    }
    __syncthreads();
    float* scratch = &S2[0][0];
    scratch[((a2 * 32 + dq) * 4 + 0) * 8 + s] = acc0;
    scratch[((a2 * 32 + dq) * 4 + 1) * 8 + s] = acc1;
    scratch[((a2 * 32 + dq) * 4 + 2) * 8 + s] = acc2;
    scratch[((a2 * 32 + dq) * 4 + 3) * 8 + s] = acc3;
  }
  __syncthreads();
  if (tid < 256) {
    const int a2 = tid >> 7, dq = (tid >> 2) & 31, k = tid & 3;
    const float* scratch = &S2[0][0];
    const float* sp = &scratch[((a2 * 32 + dq) * 4 + k) * 8];
    float tot = sp[0] + sp[1] + sp[2] + sp[3] + sp[4] + sp[5] + sp[6] + sp[7];
    const float inv = 1.f / (red[8 + a2 * 4] + red[8 + a2 * 4 + 1] +
                             red[8 + a2 * 4 + 2] + red[8 + a2 * 4 + 3]);
    att1[(size_t)bh * 1024 + (a0 + a2) * 128 + dq * 4 + k] = tot * inv;
  }
}

// ---------------- MLP MFMA GEMM with fused epilogue (unchanged) ----------------
template <int AMODE>
__global__ __launch_bounds__(256) void mlp_mfma(const float* __restrict__ A,
                                                const float* __restrict__ W,
                                                float* __restrict__ outp,
                                                int K, int N, int KC) {
  __shared__ float sW[64][33];
  const int tid = threadIdx.x;
  const int lane = tid & 63, wave = tid >> 6;
  const int wm = wave * 16;
  const int n0 = blockIdx.x * 64;
  const int kbeg = blockIdx.y * KC;
  const int l15 = lane & 15, kq8 = (lane >> 4) * 8;
  const int arow = wm + l15;

  floatx4 acc[4];
  const floatx4 zero = {0.f, 0.f, 0.f, 0.f};
#pragma unroll
  for (int j = 0; j < 4; ++j) acc[j] = zero;

  for (int kc = 0; kc < KC; kc += 32) {
    const int kbase = kbeg + kc;
    __syncthreads();
#pragma unroll
    for (int p = 0; p < 8; ++p) {
      const int k = p * 4 + wave;
      sW[lane][k] = W[(size_t)(kbase + k) * N + n0 + lane];
    }
    const float* ap;
    if (AMODE == 2) {
      const int k = kbase + kq8;
      ap = A + (size_t)(arow >> 3) * 32768 + (size_t)(k >> 9) * 4096 + (arow & 7) * 512 + (k & 511);
    } else {
      ap = A + (size_t)arow * K + kbase + kq8;
    }
    float4 a0 = *(const float4*)ap;
    float4 a1 = *(const float4*)(ap + 4);
    if (AMODE >= 1) {
      a0.x = fmaxf(a0.x, 0.f); a0.y = fmaxf(a0.y, 0.f);
      a0.z = fmaxf(a0.z, 0.f); a0.w = fmaxf(a0.w, 0.f);
      a1.x = fmaxf(a1.x, 0.f); a1.y = fmaxf(a1.y, 0.f);
      a1.z = fmaxf(a1.z, 0.f); a1.w = fmaxf(a1.w, 0.f);
    }
    short8 af;
    af[0] = (short)f2bf(a0.x); af[1] = (short)f2bf(a0.y);
    af[2] = (short)f2bf(a0.z); af[3] = (short)f2bf(a0.w);
    af[4] = (short)f2bf(a1.x); af[5] = (short)f2bf(a1.y);
    af[6] = (short)f2bf(a1.z); af[7] = (short)f2bf(a1.w);
    __syncthreads();
#pragma unroll
    for (int j = 0; j < 4; ++j) {
      const float* wp = &sW[j * 16 + l15][kq8];
      short8 bf;
      bf[0] = (short)f2bf(wp[0]); bf[1] = (short)f2bf(wp[1]);
      bf[2] = (short)f2bf(wp[2]); bf[3] = (short)f2bf(wp[3]);
      bf[4] = (short)f2bf(wp[4]); bf[5] = (short)f2bf(wp[5]);
      bf[6] = (short)f2bf(wp[6]); bf[7] = (short)f2bf(wp[7]);
      acc[j] = __builtin_amdgcn_mfma_f32_16x16x32_bf16(af, bf, acc[j], 0, 0, 0);
    }
  }
  const int q = lane >> 4;
#pragma unroll
  for (int j = 0; j < 4; ++j)
#pragma unroll
    for (int r = 0; r < 4; ++r) {
      const int m = wm + q * 4 + r;
      const int n = n0 + j * 16 + l15;
      atomicAdd(&outp[(size_t)m * N + n], acc[j][r]);
    }
}

// ---------------- attention 2 (staged): coalesced Q-read and y-write via LDS ----------------
__global__ __launch_bounds__(256) void attn2_kernel(const u16* __restrict__ qkv,
                                                    const float* __restrict__ kk,
                                                    const float* __restrict__ onet,
                                                    u16* __restrict__ y) {
  __shared__ u16 qv[256 * 132];   // Q tile, then output tile (row-private reuse)
  __shared__ float kkl[8][128];
  __shared__ float ovl[8][128];
  const int tid = threadIdx.x;
  const int chunk = blockIdx.x & 7, bh = blockIdx.x >> 3;
  const int b = bh >> 3, h = bh & 7;
  for (int i = tid; i < 1024; i += 256) {
    const int a = i >> 7, d = i & 127;
    kkl[a][d] = kk[(size_t)(b * 8 + a) * 1024 + h * 128 + d];
    ovl[a][d] = onet[(size_t)(b * 8 + a) * 1024 + h * 128 + d];
  }
  const int n0 = chunk * 256;
  const size_t qbase = ((size_t)(b * 2048 + n0)) * 3072 + h * 128;
  // stage 256 rows x 128 u16 of Q, coalesced (256B contiguous per row chunk)
#pragma unroll
  for (int p = 0; p < 32; ++p) {
    const int c = p * 256 + tid;
    const int r = c >> 5, off = (c & 31) * 4;
    *(ushort4*)&qv[r * 132 + off] = *(const ushort4*)(qkv + qbase + (size_t)r * 3072 + off);
  }
  __syncthreads();
  // per-thread row n = tid: dots from LDS
  float dots[8] = {0, 0, 0, 0, 0, 0, 0, 0};
#pragma unroll 4
  for (int dd = 0; dd < 128; dd += 4) {
    const ushort4 q4 = *(const ushort4*)&qv[tid * 132 + dd];
    const float q0 = bf2f(q4.x), q1 = bf2f(q4.y), q2 = bf2f(q4.z), q3 = bf2f(q4.w);
#pragma unroll
    for (int a = 0; a < 8; ++a) {
      const float4 k4 = *(const float4*)&kkl[a][dd];
      dots[a] += k4.x * q0 + k4.y * q1 + k4.z * q2 + k4.w * q3;
    }
  }
  const float scale = 0.0883883476483184f;
  float mx = -1e30f;
#pragma unroll
  for (int a = 0; a < 8; ++a) {
    dots[a] *= scale;
    mx = fmaxf(mx, dots[a]);
  }
  float p8[8];
  float sum = 0.f;
#pragma unroll
  for (int a = 0; a < 8; ++a) {
    p8[a] = __expf(dots[a] - mx);
    sum += p8[a];
  }
  const float inv = 1.f / sum;
#pragma unroll
  for (int a = 0; a < 8; ++a) p8[a] *= inv;
  // write output row into own LDS row (row-private: no barrier needed vs own reads)
#pragma unroll 4
  for (int dd = 0; dd < 128; dd += 4) {
    float a0 = 0, a1 = 0, a2 = 0, a3 = 0;
#pragma unroll
    for (int a = 0; a < 8; ++a) {
      const float4 o4 = *(const float4*)&ovl[a][dd];
      a0 += p8[a] * o4.x;
      a1 += p8[a] * o4.y;
      a2 += p8[a] * o4.z;
      a3 += p8[a] * o4.w;
    }
    ushort4 o;
    o.x = f2bf(a0);
    o.y = f2bf(a1);
    o.z = f2bf(a2);
    o.w = f2bf(a3);
    *(ushort4*)&qv[tid * 132 + dd] = o;
  }
  __syncthreads();
  // cooperative coalesced store of the output tile
  const size_t ybase = ((size_t)(b * 2048 + n0)) * 1024 + h * 128;
#pragma unroll
  for (int p = 0; p < 32; ++p) {
    const int c = p * 256 + tid;
    const int r = c >> 5, off = (c & 31) * 4;
    *(ushort4*)(y + ybase + (size_t)r * 1024 + off) = *(const ushort4*)&qv[r * 132 + off];
  }
}

extern "C" void kernel_launch(void* const* d_in, const int* in_sizes, int n_in,
                              void* d_out, int out_size, void* d_ws, size_t ws_size,
                              hipStream_t stream) {
  const float* inputs = (const float*)d_in[0];
  const float* ln_g = (const float*)d_in[1];
  const float* ln_b = (const float*)d_in[2];
  const float* q_anchor = (const float*)d_in[3];
  const float* W_qkv = (const float*)d_in[4];
  const float* b_qkv = (const float*)d_in[5];
  const float* W_an = (const float*)d_in[6];
  const float* b_an = (const float*)d_in[7];
  const float* W_n1 = (const float*)d_in[8];
  const float* b_n1 = (const float*)d_in[9];
  const float* W_n2 = (const float*)d_in[10];
  const float* b_n2 = (const float*)d_in[11];
  const float* W_n3 = (const float*)d_in[12];
  const float* b_n3 = (const float*)d_in[13];
  const float* W_k = (const float*)d_in[14];
  const float* b_k = (const float*)d_in[15];
  const float* W_o = (const float*)d_in[16];
  const float* b_o = (const float*)d_in[17];
  float* out = (float*)d_out;

  char* ws = (char*)d_ws;
  u16* qkv = (u16*)(ws);                                   // 16384*3072 bf16 = 96 MB
  u16* xbf = (u16*)(ws + 100663296);                       // 16384*1024 bf16 (x, later y)
  u16* WqkvT = (u16*)(ws + 134217728);                     // 3072*1024 bf16
  u16* WoT = (u16*)(ws + 140509184);                       // 1024*1024 bf16
  float* att1 = (float*)(ws + 142606336);                  // 64*1024
  float* anp = (float*)(ws + 142868480);                   // 64*4096 (raw, pre-relu/perm)
  float* h1 = (float*)(ws + 143917056);                    // 64*1024
  float* h2 = (float*)(ws + 144179200);                    // 64*4096 (raw, pre-relu)
  float* onet = (float*)(ws + 145227776);                  // 64*1024
  float* kkb = (float*)(ws + 145489920);                   // 64*1024

  // 1) prep: LayerNorm + weight transposes + bias prefill (one launch)
  prep_kernel<<<21184, 256, 0, stream>>>(inputs, ln_g, ln_b, xbf,
                                         W_qkv, WqkvT, W_o, WoT,
                                         b_an, b_n1, b_n2, b_n3, b_k,
                                         anp, h1, h2, onet, kkb);
  // 2) QKV GEMM, split into 3 column-chunk launches (diagnostic: lowers top-5 ceiling)
  for (int c = 0; c < 3; ++c) {
    gemm_bf16<0><<<dim3(64, 4), 512, 0, stream>>>(
        xbf, WqkvT + (size_t)c * 1024 * 1024, b_qkv + c * 1024, nullptr,
        qkv + (size_t)c * 1024, nullptr, 16384, 3072, 1024);
  }
  // 3) fused anchor attention -> att1
  attn1_fused<<<256, 512, 0, stream>>>(qkv, q_anchor, att1);
  // 4) MLP chain: split-K MFMA GEMMs, atomic-accumulated into bias-preinit outputs
  mlp_mfma<0><<<dim3(64, 4), 256, 0, stream>>>(att1, W_an, anp, 1024, 4096, 256);
  mlp_mfma<2><<<dim3(16, 16), 256, 0, stream>>>(anp, W_n1, h1, 4096, 1024, 256);
  mlp_mfma<0><<<dim3(64, 4), 256, 0, stream>>>(h1, W_n2, h2, 1024, 4096, 256);
  mlp_mfma<1><<<dim3(16, 16), 256, 0, stream>>>(h2, W_n3, onet, 4096, 1024, 256);
  mlp_mfma<0><<<dim3(16, 8), 256, 0, stream>>>(onet, W_k, kkb, 1024, 1024, 128);
  // 5) query attention over 8 anchors -> y bf16 (staged, coalesced)
  attn2_kernel<<<512, 256, 0, stream>>>(qkv, kkb, onet, xbf);
  // 6) output GEMM + bias + residual -> d_out f32
  gemm_bf16<1><<<dim3(64, 4), 512, 0, stream>>>(xbf, WoT, b_o, inputs, nullptr, out,
                                                16384, 1024, 1024);
}